// Round 12
// baseline (147.960 us; speedup 1.0000x reference)
//
#include <hip/hip_runtime.h>
#include <math.h>

#define B_   2
#define LQ_  10723
#define D_   256
#define NH_  8
#define HD_  32
#define NL_  4
#define NP_  4
#define DFF_ 1024
#define M_   (B_ * LQ_)   // 21446

typedef __attribute__((ext_vector_type(4))) float f32x4;
typedef __attribute__((ext_vector_type(8))) short short8;
typedef __attribute__((ext_vector_type(4))) unsigned short us4;
typedef __attribute__((ext_vector_type(8))) unsigned short us8;
typedef __attribute__((ext_vector_type(4))) unsigned int u32x4;

__device__ __forceinline__ unsigned short f2bf(float f) {
    union { float f; unsigned int u; } x; x.f = f;
    unsigned int r = x.u + 0x7FFF + ((x.u >> 16) & 1);   // RNE
    return (unsigned short)(r >> 16);
}
__device__ __forceinline__ float bf2f(unsigned short u) {
    union { unsigned int u; float f; } x; x.u = (unsigned int)u << 16;
    return x.f;
}
__device__ __forceinline__ float bflo(unsigned int u) {
    union { unsigned int u; float f; } x; x.u = u << 16; return x.f;
}
__device__ __forceinline__ float bfhi(unsigned int u) {
    union { unsigned int u; float f; } x; x.u = u & 0xffff0000u; return x.f;
}

#define AS3U(p) ((__attribute__((address_space(3))) unsigned int*)(uintptr_t)(p))
#define AS1U(p) ((const __attribute__((address_space(1))) unsigned int*)(uintptr_t)(p))

// ---------------------------------------------------------------------------
// Fused prep: weight transpose/convert + bias concat + activation convert.
// ---------------------------------------------------------------------------
__global__ __launch_bounds__(256) void prep_kernel(
    const float* __restrict__ Wv, const float* __restrict__ Woff,
    const float* __restrict__ Wattn, const float* __restrict__ Wout,
    const float* __restrict__ W1, const float* __restrict__ W2,
    const float* __restrict__ b_off, const float* __restrict__ b_attn,
    const float* __restrict__ value, const float* __restrict__ query,
    const float* __restrict__ qpos,
    unsigned short* __restrict__ WvT, unsigned short* __restrict__ WoaT,
    unsigned short* __restrict__ WoutT, unsigned short* __restrict__ W1T,
    unsigned short* __restrict__ W2T, float* __restrict__ b_oa,
    unsigned short* __restrict__ v16, unsigned short* __restrict__ q16, int n4)
{
    int idx = blockIdx.x * 256 + threadIdx.x;
    if (idx < 65536) {
        int n = idx >> 8, k = idx & 255;
        WvT[idx] = f2bf(Wv[k * 256 + n]);
    } else if (idx < 163840) {
        int l = idx - 65536; int n = l >> 8, k = l & 255;
        WoaT[l] = f2bf(n < 256 ? Woff[k * 256 + n] : Wattn[k * 128 + (n - 256)]);
    } else if (idx < 229376) {
        int l = idx - 163840; int n = l >> 8, k = l & 255;
        WoutT[l] = f2bf(Wout[k * 256 + n]);
    } else if (idx < 491520) {
        int l = idx - 229376; int n = l >> 8, k = l & 255;
        W1T[l] = f2bf(W1[k * 1024 + n]);
    } else if (idx < 753664) {
        int l = idx - 491520; int n = l >> 10, k = l & 1023;
        W2T[l] = f2bf(W2[k * 256 + n]);
    } else if (idx < 754048) {
        int l = idx - 753664;
        b_oa[l] = (l < 256) ? b_off[l] : b_attn[l - 256];
    } else if (idx < 754048 + n4) {
        int i = idx - 754048;
        float4 v = reinterpret_cast<const float4*>(value)[i];
        us4 r = { f2bf(v.x), f2bf(v.y), f2bf(v.z), f2bf(v.w) };
        reinterpret_cast<us4*>(v16)[i] = r;
    } else if (idx < 754048 + 2 * n4) {
        int j = idx - 754048 - n4;
        float4 va = reinterpret_cast<const float4*>(query)[j];
        float4 vb = reinterpret_cast<const float4*>(qpos)[j];
        us4 r = { f2bf(va.x + vb.x), f2bf(va.y + vb.y), f2bf(va.z + vb.z), f2bf(va.w + vb.w) };
        reinterpret_cast<us4*>(q16)[j] = r;
    }
}

// ---------------------------------------------------------------------------
// Fused vproj + off/attn GEMM dispatch. 128x128 tile, BK=32, K=256, 2-phase.
// XCD-chunked swizzle: 840 blocks = 8 XCDs x (21 row-bands x 5 cols).
// vproj path: LDS-staged epilogue -> coalesced 16B head-major writes.
// ---------------------------------------------------------------------------
__global__ __launch_bounds__(256) void gemm_pre(
    const unsigned short* __restrict__ v16, const unsigned short* __restrict__ q16,
    const unsigned short* __restrict__ WvT, const unsigned short* __restrict__ WoaT,
    const float* __restrict__ b_v, const float* __restrict__ b_oa,
    unsigned short* __restrict__ vph, float* __restrict__ oa)
{
    __shared__ unsigned short SM[2][2][128 * 32];

    const int i   = (int)blockIdx.y * 5 + (int)blockIdx.x;
    const int xcd = i & 7;
    const int jj  = i >> 3;            // 0..104
    const int by  = xcd * 21 + jj / 5;
    const int bx  = jj % 5;

    const bool is_v = (bx < 2);
    const unsigned short* A  = is_v ? v16 : q16;
    const unsigned short* BT = is_v ? WvT : WoaT;
    const float* bias = is_v ? b_v : b_oa;
    const int n0 = (is_v ? bx : bx - 2) * 128;
    const int K = 256;

    const int tid  = threadIdx.x;
    const int wave = tid >> 6;
    const int lane = tid & 63;
    const int m0 = by * 128;
    const int wr = (wave >> 1) * 64;
    const int wc = (wave & 1) * 64;

    f32x4 acc[4][4] = {};
    const int soff = wave * 1024 + lane * 16;

    auto stage = [&](int buf, int k0) {
        #pragma unroll
        for (int p = 0; p < 2; ++p) {
            const int off  = p * 4096 + soff;
            const int row  = off >> 6;
            const int colb = off & 63;
            int ar = m0 + row; ar = (ar < M_) ? ar : (M_ - 1);
            __builtin_amdgcn_global_load_lds(AS1U(A + (size_t)ar * K + k0 + (colb >> 1)),
                AS3U(&SM[0][buf][(p * 4096 + wave * 1024) >> 1]), 16, 0, 0);
            __builtin_amdgcn_global_load_lds(AS1U(BT + (size_t)(n0 + row) * K + k0 + (colb >> 1)),
                AS3U(&SM[1][buf][(p * 4096 + wave * 1024) >> 1]), 16, 0, 0);
        }
    };

    stage(0, 0);
    __syncthreads();
    int cur = 0;
    for (int t = 0; t < 8; ++t) {
        if (t + 1 < 8) stage(cur ^ 1, (t + 1) * 32);
        const int fr = lane & 15;
        const int kb = (lane >> 4) * 8;
        short8 af[4], bf[4];
        #pragma unroll
        for (int m = 0; m < 4; ++m)
            af[m] = *reinterpret_cast<const short8*>(&SM[0][cur][(wr + m * 16 + fr) * 32 + kb]);
        #pragma unroll
        for (int n = 0; n < 4; ++n)
            bf[n] = *reinterpret_cast<const short8*>(&SM[1][cur][(wc + n * 16 + fr) * 32 + kb]);
        #pragma unroll
        for (int m = 0; m < 4; ++m)
            #pragma unroll
            for (int n = 0; n < 4; ++n)
                acc[m][n] = __builtin_amdgcn_mfma_f32_16x16x32_bf16(af[m], bf[n], acc[m][n], 0, 0, 0);
        if (t + 1 < 8) { __syncthreads(); cur ^= 1; }
    }

    const int fr = lane & 15;
    const int r0 = (lane >> 4) * 4;
    if (is_v) {
        __syncthreads();
        unsigned short* Ct = &SM[0][0][0];   // 128x128 bf16 = 32 KB
        #pragma unroll
        for (int n = 0; n < 4; ++n) {
            const float bv = bias[n0 + wc + n * 16 + fr];
            #pragma unroll
            for (int m = 0; m < 4; ++m)
                #pragma unroll
                for (int r = 0; r < 4; ++r)
                    Ct[(wr + m * 16 + r0 + r) * 128 + wc + n * 16 + fr] = f2bf(acc[m][n][r] + bv);
        }
        __syncthreads();
        #pragma unroll
        for (int pass = 0; pass < 8; ++pass) {
            const int r  = pass * 16 + (tid >> 4);
            const int c8 = (tid & 15) * 8;
            const int row = m0 + r;
            if (row < M_) {
                const int col = n0 + c8;
                const int bb = (row >= LQ_) ? 1 : 0;
                const int lvv = row - bb * LQ_;
                const int hh = col >> 5, dd = col & 31;
                us8 v = *reinterpret_cast<const us8*>(&Ct[r * 128 + c8]);
                *reinterpret_cast<us8*>(&vph[(((size_t)bb * NH_ + hh) * LQ_ + lvv) * 32 + dd]) = v;
            }
        }
    } else {
        #pragma unroll
        for (int n = 0; n < 4; ++n) {
            const int col = n0 + wc + n * 16 + fr;
            const float bv = bias[col];
            #pragma unroll
            for (int m = 0; m < 4; ++m) {
                #pragma unroll
                for (int r = 0; r < 4; ++r) {
                    const int row = m0 + wr + m * 16 + r0 + r;
                    if (row < M_) oa[(size_t)row * 384 + col] = acc[m][n][r] + bv;
                }
            }
        }
    }
}

// ---------------------------------------------------------------------------
// GEMM (N=256) + bias + residual + LayerNorm (LN1). 2-phase double-buffered.
// BM=64, BN=256, BK=32, 512 threads = 8 waves. f32 residual, bf16 output
// via LDS-coalesced epilogue.
// ---------------------------------------------------------------------------
__global__ __launch_bounds__(512) void gemm_ln1(
    const unsigned short* __restrict__ A,
    const unsigned short* __restrict__ BT,
    const float* __restrict__ bias,
    const float* __restrict__ res,
    const float* __restrict__ g,
    const float* __restrict__ beta,
    unsigned short* __restrict__ out16,
    int M, int K)
{
    __shared__ unsigned short As[2][64 * 32];
    __shared__ unsigned short Bs[2][256 * 32];   // doubles as 64x256 bf16 out tile
    __shared__ float2 sRed[4][64];

    const int tid  = threadIdx.x;
    const int wave = tid >> 6;
    const int lane = tid & 63;
    const int m0 = blockIdx.x * 64;
    const int wr = (wave >> 2) * 32;
    const int wc = (wave & 3) * 64;

    f32x4 acc[2][4] = {};

    auto stage = [&](int buf, int k0) {
        if (tid < 256) {
            const int off  = tid * 16;
            const int row  = off >> 6;
            const int colb = off & 63;
            int ar = m0 + row; ar = (ar < M) ? ar : (M - 1);
            __builtin_amdgcn_global_load_lds(AS1U(A + (size_t)ar * K + k0 + (colb >> 1)),
                AS3U(&As[buf][(wave * 1024) >> 1]), 16, 0, 0);
        }
        #pragma unroll
        for (int p = 0; p < 2; ++p) {
            const int off  = p * 8192 + tid * 16;
            const int row  = off >> 6;
            const int colb = off & 63;
            __builtin_amdgcn_global_load_lds(AS1U(BT + (size_t)row * K + k0 + (colb >> 1)),
                AS3U(&Bs[buf][(p * 8192 + wave * 1024) >> 1]), 16, 0, 0);
        }
    };

    const int nt = K >> 5;
    stage(0, 0);
    __syncthreads();
    int cur = 0;
    for (int t = 0; t < nt; ++t) {
        if (t + 1 < nt) stage(cur ^ 1, (t + 1) * 32);
        const int fr = lane & 15;
        const int kb = (lane >> 4) * 8;
        short8 af[2], bf[4];
        #pragma unroll
        for (int m = 0; m < 2; ++m)
            af[m] = *reinterpret_cast<const short8*>(&As[cur][(wr + m * 16 + fr) * 32 + kb]);
        #pragma unroll
        for (int n = 0; n < 4; ++n)
            bf[n] = *reinterpret_cast<const short8*>(&Bs[cur][(wc + n * 16 + fr) * 32 + kb]);
        #pragma unroll
        for (int m = 0; m < 2; ++m)
            #pragma unroll
            for (int n = 0; n < 4; ++n)
                acc[m][n] = __builtin_amdgcn_mfma_f32_16x16x32_bf16(af[m], bf[n], acc[m][n], 0, 0, 0);
        if (t + 1 < nt) { __syncthreads(); cur ^= 1; }
    }

    const int fr = lane & 15;
    const int r0 = (lane >> 4) * 4;
    float biasv[4], gv[4], bev[4];
    #pragma unroll
    for (int n = 0; n < 4; ++n) {
        const int col = wc + n * 16 + fr;
        biasv[n] = bias[col]; gv[n] = g[col]; bev[n] = beta[col];
    }
    #pragma unroll
    for (int m = 0; m < 2; ++m) {
        #pragma unroll
        for (int r = 0; r < 4; ++r) {
            int row = m0 + wr + m * 16 + r0 + r;
            int rr = (row < M) ? row : (M - 1);
            const float* rp = res + (size_t)rr * 256;
            #pragma unroll
            for (int n = 0; n < 4; ++n)
                acc[m][n][r] += biasv[n] + rp[wc + n * 16 + fr];
        }
    }
    #pragma unroll
    for (int m = 0; m < 2; ++m) {
        #pragma unroll
        for (int r = 0; r < 4; ++r) {
            float sx = 0.f, sxx = 0.f;
            #pragma unroll
            for (int n = 0; n < 4; ++n) { float t = acc[m][n][r]; sx += t; sxx += t * t; }
            #pragma unroll
            for (int mask = 1; mask < 16; mask <<= 1) {
                sx  += __shfl_xor(sx, mask);
                sxx += __shfl_xor(sxx, mask);
            }
            if (fr == 0) sRed[wave & 3][wr + m * 16 + r0 + r] = make_float2(sx, sxx);
        }
    }
    __syncthreads();
    unsigned short* Ct = &Bs[0][0];   // 64x256 bf16
    #pragma unroll
    for (int m = 0; m < 2; ++m) {
        #pragma unroll
        for (int r = 0; r < 4; ++r) {
            const int lr = wr + m * 16 + r0 + r;
            float2 a0 = sRed[0][lr], a1 = sRed[1][lr], a2 = sRed[2][lr], a3 = sRed[3][lr];
            const float S  = a0.x + a1.x + a2.x + a3.x;
            const float SS = a0.y + a1.y + a2.y + a3.y;
            const float mean = S * (1.f / 256.f);
            const float var  = SS * (1.f / 256.f) - mean * mean;
            const float rstd = rsqrtf(var + 1e-5f);
            #pragma unroll
            for (int n = 0; n < 4; ++n) {
                const int col = wc + n * 16 + fr;
                const float y = (acc[m][n][r] - mean) * rstd * gv[n] + bev[n];
                Ct[lr * 256 + col] = f2bf(y);
            }
        }
    }
    __syncthreads();
    #pragma unroll
    for (int pass = 0; pass < 4; ++pass) {
        const int rrow = pass * 16 + (tid >> 5);
        const int cb = (tid & 31) * 8;
        const int grow = m0 + rrow;
        if (grow < M) {
            us8 v = *reinterpret_cast<const us8*>(&Ct[rrow * 256 + cb]);
            *reinterpret_cast<us8*>(&out16[(size_t)grow * 256 + cb]) = v;
        }
    }
}

// ---------------------------------------------------------------------------
// Fused FFN: out = LN(q1b + relu(q1b@W1^T+b1)@W2^T + b2).
// Per 64-row block: q1b tile resident in LDS (padded, 2-way-bank-free);
// 8 chunks of 128 h-cols: GEMM-A (h chunk -> LDS) then GEMM-B (C += h@W2).
// h never hits HBM; LN residual read from the Aq LDS tile.
// 512 threads = 8 waves. LDS ~68 KB -> 2 blocks/CU.
// ---------------------------------------------------------------------------
#define AQ_S 264   // 256 + 8 pad (2-way bank access on stride-528B rows)
#define HC_S 136   // 128 + 8 pad
__global__ __launch_bounds__(512) void gemm_ffn_ln(
    const unsigned short* __restrict__ Aq16,   // q1b (M,256) bf16
    const unsigned short* __restrict__ W1T,    // (1024,256) bf16
    const float* __restrict__ b1,
    const unsigned short* __restrict__ W2T,    // (256,1024) bf16
    const float* __restrict__ b2,
    const float* __restrict__ g,
    const float* __restrict__ beta,
    float* __restrict__ outf,
    int M)
{
    __shared__ unsigned short Aq[64 * AQ_S];     // 33 KB
    __shared__ unsigned short Hc[64 * HC_S];     // 17 KB
    __shared__ unsigned short Wst[2][128 * 32];  // 16 KB (A: 2x8KB dbuf; B: 16KB linear)
    __shared__ float2 sRed[4][64];

    const int tid  = threadIdx.x;
    const int wave = tid >> 6;
    const int lane = tid & 63;
    const int m0 = blockIdx.x * 64;
    const int fr = lane & 15;
    const int kb = (lane >> 4) * 8;
    const int r0 = (lane >> 4) * 4;

    // ---- stage Aq via registers (padded rows; global_load_lds can't pad) ----
    #pragma unroll
    for (int p = 0; p < 4; ++p) {
        const int off = p * 8192 + tid * 16;   // source byte offset (512B rows)
        const int row = off >> 9;
        const int colb = off & 511;
        int ar = m0 + row; ar = (ar < M) ? ar : (M - 1);
        us8 v = *reinterpret_cast<const us8*>(Aq16 + (size_t)ar * 256 + (colb >> 1));
        *reinterpret_cast<us8*>(Aq + row * AQ_S + (colb >> 1)) = v;
    }

    const int wrA = (wave >> 2) * 32, wcA = (wave & 3) * 32;   // phase A: 64x128
    const int wrB = (wave >> 2) * 32, wcB = (wave & 3) * 64;   // phase B: 64x256

    f32x4 accC[2][4] = {};

    __syncthreads();   // Aq resident

    for (int c = 0; c < 8; ++c) {
        // ======== phase A: Hc = relu(Aq @ W1T[c*128..]^T + b1) ========
        f32x4 accH[2][2] = {};
        {   // prologue: W1 subtile (128 x 32) -> Wst[0]
            const int off = tid * 16;
            const int row = off >> 6;
            __builtin_amdgcn_global_load_lds(
                AS1U(W1T + (size_t)(c * 128 + row) * 256 + ((off & 63) >> 1)),
                AS3U(&Wst[0][off >> 1]), 16, 0, 0);
        }
        __syncthreads();
        for (int t = 0; t < 8; ++t) {
            if (t + 1 < 8) {
                const int off = tid * 16;
                const int row = off >> 6;
                __builtin_amdgcn_global_load_lds(
                    AS1U(W1T + (size_t)(c * 128 + row) * 256 + (t + 1) * 32 + ((off & 63) >> 1)),
                    AS3U(&Wst[(t + 1) & 1][off >> 1]), 16, 0, 0);
            }
            short8 af[2], bf[2];
            #pragma unroll
            for (int m = 0; m < 2; ++m)
                af[m] = *reinterpret_cast<const short8*>(Aq + (wrA + m * 16 + fr) * AQ_S + t * 32 + kb);
            #pragma unroll
            for (int n = 0; n < 2; ++n)
                bf[n] = *reinterpret_cast<const short8*>(&Wst[t & 1][(wcA + n * 16 + fr) * 32 + kb]);
            #pragma unroll
            for (int m = 0; m < 2; ++m)
                #pragma unroll
                for (int n = 0; n < 2; ++n)
                    accH[m][n] = __builtin_amdgcn_mfma_f32_16x16x32_bf16(af[m], bf[n], accH[m][n], 0, 0, 0);
            if (t + 1 < 8) __syncthreads();
        }
        // bias + relu -> Hc (own-acc dependency only)
        #pragma unroll
        for (int n = 0; n < 2; ++n) {
            const float bv = b1[c * 128 + wcA + n * 16 + fr];
            #pragma unroll
            for (int m = 0; m < 2; ++m)
                #pragma unroll
                for (int r = 0; r < 4; ++r)
                    Hc[(wrA + m * 16 + r0 + r) * HC_S + wcA + n * 16 + fr] =
                        f2bf(fmaxf(accH[m][r == 0 ? n : n][r] + bv, 0.f));
        }
        __syncthreads();   // Hc visible; all phase-A MFMA done -> Wst free

        // ======== phase B: accC += Hc @ W2T[:, c*128..]^T ========
        for (int tt = 0; tt < 4; ++tt) {
            #pragma unroll
            for (int p = 0; p < 2; ++p) {   // W2 subtile (256 x 32) -> Wst linear
                const int off = p * 8192 + tid * 16;
                const int row = off >> 6;
                __builtin_amdgcn_global_load_lds(
                    AS1U(W2T + (size_t)row * 1024 + c * 128 + tt * 32 + ((off & 63) >> 1)),
                    AS3U(&Wst[0][0] + (off >> 1)), 16, 0, 0);
            }
            __syncthreads();   // W2 tile ready (vmcnt drained)
            short8 af[2], bf[4];
            #pragma unroll
            for (int m = 0; m < 2; ++m)
                af[m] = *reinterpret_cast<const short8*>(Hc + (wrB + m * 16 + fr) * HC_S + tt * 32 + kb);
            #pragma unroll
            for (int n = 0; n < 4; ++n)
                bf[n] = *reinterpret_cast<const short8*>(&Wst[0][0] + (wcB + n * 16 + fr) * 32 + kb);
            #pragma unroll
            for (int m = 0; m < 2; ++m)
                #pragma unroll
                for (int n = 0; n < 4; ++n)
                    accC[m][n] = __builtin_amdgcn_mfma_f32_16x16x32_bf16(af[m], bf[n], accC[m][n], 0, 0, 0);
            __syncthreads();   // MFMA done before next Wst overwrite
        }
    }

    // ======== epilogue: bias + residual (from Aq LDS) + LayerNorm ========
    float b2v[4], gv[4], bev[4];
    #pragma unroll
    for (int n = 0; n < 4; ++n) {
        const int col = wcB + n * 16 + fr;
        b2v[n] = b2[col]; gv[n] = g[col]; bev[n] = beta[col];
    }
    #pragma unroll
    for (int m = 0; m < 2; ++m) {
        #pragma unroll
        for (int r = 0; r < 4; ++r) {
            const int lr = wrB + m * 16 + r0 + r;
            #pragma unroll
            for (int n = 0; n < 4; ++n)
                accC[m][n][r] += b2v[n] + bf2f(Aq[lr * AQ_S + wcB + n * 16 + fr]);
        }
    }
    #pragma unroll
    for (int m = 0; m < 2; ++m) {
        #pragma unroll
        for (int r = 0; r < 4; ++r) {
            float sx = 0.f, sxx = 0.f;
            #pragma unroll
            for (int n = 0; n < 4; ++n) { float t = accC[m][n][r]; sx += t; sxx += t * t; }
            #pragma unroll
            for (int mask = 1; mask < 16; mask <<= 1) {
                sx  += __shfl_xor(sx, mask);
                sxx += __shfl_xor(sxx, mask);
            }
            if (fr == 0) sRed[wave & 3][wrB + m * 16 + r0 + r] = make_float2(sx, sxx);
        }
    }
    __syncthreads();
    #pragma unroll
    for (int m = 0; m < 2; ++m) {
        #pragma unroll
        for (int r = 0; r < 4; ++r) {
            const int lr = wrB + m * 16 + r0 + r;
            float2 a0 = sRed[0][lr], a1 = sRed[1][lr], a2 = sRed[2][lr], a3 = sRed[3][lr];
            const float S  = a0.x + a1.x + a2.x + a3.x;
            const float SS = a0.y + a1.y + a2.y + a3.y;
            const float mean = S * (1.f / 256.f);
            const float var  = SS * (1.f / 256.f) - mean * mean;
            const float rstd = rsqrtf(var + 1e-5f);
            const int row = m0 + lr;
            if (row < M) {
                #pragma unroll
                for (int n = 0; n < 4; ++n) {
                    const int col = wcB + n * 16 + fr;
                    outf[(size_t)row * 256 + col] = (accC[m][n][r] - mean) * rstd * gv[n] + bev[n];
                }
            }
        }
    }
}

// ---------------------------------------------------------------------------
// Multi-scale deformable attention, XCD-local by head (round-9 structure:
// 4 lanes/query x 16B, depth-2 pipelined gathers).
// ---------------------------------------------------------------------------
__global__ __launch_bounds__(256) void msdeform_kernel(
    const unsigned short* __restrict__ vproj_h, const float* __restrict__ offattn,
    const float* __restrict__ refp, unsigned short* __restrict__ msout)
{
    __shared__ int4   sIdx[4][16][17];
    __shared__ float4 sWgt[4][16][17];

    const int bh = blockIdx.x & 15;          // b*8 + h
    const int qc = blockIdx.x >> 4;
    const int b  = bh >> 3;
    const int h  = bh & 7;
    const int wave = threadIdx.x >> 6;
    const int lane = threadIdx.x & 63;
    const int qq = lane >> 2;                // query within wave (0..15)
    const int j  = lane & 3;                 // level (ph1) / channel-octet (ph2)
    const int lv = qc * 64 + wave * 16 + qq;
    if (lv >= LQ_) return;
    const int bq = b * LQ_ + lv;

    // ---- phase 1: level j, points 4j..4j+3 ----
    const float4 oA = *reinterpret_cast<const float4*>(offattn + (size_t)bq * 384 + h * 32 + 8 * j);
    const float4 oB = *reinterpret_cast<const float4*>(offattn + (size_t)bq * 384 + h * 32 + 8 * j + 4);
    const float4 lg = *reinterpret_cast<const float4*>(offattn + (size_t)bq * 384 + 256 + h * 16 + 4 * j);
    const float2 rp = *reinterpret_cast<const float2*>(refp + (size_t)bq * 8 + 2 * j);

    const float Wf[4] = {106.f, 53.f, 27.f, 14.f};
    const float Hf[4] = {76.f, 38.f, 19.f, 10.f};
    const int   Wi[4] = {106, 53, 27, 14};
    const int   Hi[4] = {76, 38, 19, 10};
    const int   St[4] = {0, 8056, 10070, 10583};

    float mx = fmaxf(fmaxf(lg.x, lg.y), fmaxf(lg.z, lg.w));
    mx = fmaxf(mx, __shfl_xor(mx, 1));
    mx = fmaxf(mx, __shfl_xor(mx, 2));
    const float e0 = __expf(lg.x - mx), e1 = __expf(lg.y - mx);
    const float e2 = __expf(lg.z - mx), e3 = __expf(lg.w - mx);
    float s = e0 + e1 + e2 + e3;
    s += __shfl_xor(s, 1); s += __shfl_xor(s, 2);
    const float inv = 1.f / s;

    const int W = Wi[j], H = Hi[j];
    const float Wff = Wf[j], Hff = Hf[j];
    const int base = St[j];
    const float oxs[4] = {oA.x, oA.z, oB.x, oB.z};
    const float oys[4] = {oA.y, oA.w, oB.y, oB.w};
    const float ews[4] = {e0, e1, e2, e3};

    #pragma unroll
    for (int i = 0; i < 4; ++i) {
        const float aw = ews[i] * inv;
        const float x = fmaf(rp.x, Wff, oxs[i]) - 0.5f;
        const float y = fmaf(rp.y, Hff, oys[i]) - 0.5f;
        const float xf = floorf(x), yf = floorf(y);
        const float fx = x - xf, fy = y - yf;
        const int x0 = (int)xf, y0 = (int)yf;
        const float gx = 1.f - fx, gy = 1.f - fy;
        const bool vx0 = (x0 >= 0) && (x0 < W);
        const bool vx1 = (x0 + 1 >= 0) && (x0 + 1 < W);
        const bool vy0 = (y0 >= 0) && (y0 < H);
        const bool vy1 = (y0 + 1 >= 0) && (y0 + 1 < H);
        const int xc0 = min(max(x0, 0), W - 1);
        const int xc1 = min(max(x0 + 1, 0), W - 1);
        const int yr0 = min(max(y0, 0), H - 1) * W;
        const int yr1 = min(max(y0 + 1, 0), H - 1) * W;
        int4 iv; float4 wv;
        iv.x = (base + yr0 + xc0) << 6;  wv.x = (vx0 && vy0) ? gx * gy * aw : 0.f;
        iv.y = (base + yr0 + xc1) << 6;  wv.y = (vx1 && vy0) ? fx * gy * aw : 0.f;
        iv.z = (base + yr1 + xc0) << 6;  wv.z = (vx0 && vy1) ? gx * fy * aw : 0.f;
        iv.w = (base + yr1 + xc1) << 6;  wv.w = (vx1 && vy1) ? fx * fy * aw : 0.f;
        sIdx[wave][qq][4 * j + i] = iv;
        sWgt[wave][qq][4 * j + i] = wv;
    }

    // ---- phase 2: depth-2 pipelined gather, 16 B/lane/corner ----
    const char* vb = (const char*)(vproj_h + (size_t)bh * LQ_ * 32) + j * 16;
    f32x4 accA = {0.f, 0.f, 0.f, 0.f};
    f32x4 accB = {0.f, 0.f, 0.f, 0.f};

    int4 iv0 = sIdx[wave][qq][0];
    u32x4 a0 = *reinterpret_cast<const u32x4*>(vb + (unsigned)iv0.x);
    u32x4 a1 = *reinterpret_cast<const u32x4*>(vb + (unsigned)iv0.y);
    u32x4 a2 = *reinterpret_cast<const u32x4*>(vb + (unsigned)iv0.z);
    u32x4 a3 = *reinterpret_cast<const u32x4*>(vb + (unsigned)iv0.w);

    #pragma unroll
    for (int p = 0; p < 16; ++p) {
        u32x4 b0, b1, b2, b3;
        if (p < 15) {
            const int4 nv = sIdx[wave][qq][p + 1];
            b0 = *reinterpret_cast<const u32x4*>(vb + (unsigned)nv.x);
            b1 = *reinterpret_cast<const u32x4*>(vb + (unsigned)nv.y);
            b2 = *reinterpret_cast<const u32x4*>(vb + (unsigned)nv.z);
            b3 = *reinterpret_cast<const u32x4*>(vb + (unsigned)nv.w);
        }
        const float4 wv = sWgt[wave][qq][p];
        accA[0] = fmaf(wv.x, bflo(a0.x), accA[0]); accA[1] = fmaf(wv.x, bfhi(a0.x), accA[1]);
        accA[2] = fmaf(wv.x, bflo(a0.y), accA[2]); accA[3] = fmaf(wv.x, bfhi(a0.y), accA[3]);
        accB[0] = fmaf(wv.x, bflo(a0.z), accB[0]); accB[1] = fmaf(wv.x, bfhi(a0.z), accB[1]);
        accB[2] = fmaf(wv.x, bflo(a0.w), accB[2]); accB[3] = fmaf(wv.x, bfhi(a0.w), accB[3]);
        accA[0] = fmaf(wv.y, bflo(a1.x), accA[0]); accA[1] = fmaf(wv.y, bfhi(a1.x), accA[1]);
        accA[2] = fmaf(wv.y, bflo(a1.y), accA[2]); accA[3] = fmaf(wv.y, bfhi(a1.y), accA[3]);
        accB[0] = fmaf(wv.y, bflo(a1.z), accB[0]); accB[1] = fmaf(wv.y, bfhi(a1.z), accB[1]);
        accB[2] = fmaf(wv.y, bflo(a1.w), accB[2]); accB[3] = fmaf(wv.y, bfhi(a1.w), accB[3]);
        accA[0] = fmaf(wv.z, bflo(a2.x), accA[0]); accA[1] = fmaf(wv.z, bfhi(a2.x), accA[1]);
        accA[2] = fmaf(wv.z, bflo(a2.y), accA[2]); accA[3] = fmaf(wv.z, bfhi(a2.y), accA[3]);
        accB[0] = fmaf(wv.z, bflo(a2.z), accB[0]); accB[1] = fmaf(wv.z, bfhi(a2.z), accB[1]);
        accB[2] = fmaf(wv.z, bflo(a2.w), accB[2]); accB[3] = fmaf(wv.z, bfhi(a2.w), accB[3]);
        accA[0] = fmaf(wv.w, bflo(a3.x), accA[0]); accA[1] = fmaf(wv.w, bfhi(a3.x), accA[1]);
        accA[2] = fmaf(wv.w, bflo(a3.y), accA[2]); accA[3] = fmaf(wv.w, bfhi(a3.y), accA[3]);
        accB[0] = fmaf(wv.w, bflo(a3.z), accB[0]); accB[1] = fmaf(wv.w, bfhi(a3.z), accB[1]);
        accB[2] = fmaf(wv.w, bflo(a3.w), accB[2]); accB[3] = fmaf(wv.w, bfhi(a3.w), accB[3]);
        a0 = b0; a1 = b1; a2 = b2; a3 = b3;
    }
    us8 r = { f2bf(accA[0]), f2bf(accA[1]), f2bf(accA[2]), f2bf(accA[3]),
              f2bf(accB[0]), f2bf(accB[1]), f2bf(accB[2]), f2bf(accB[3]) };
    *reinterpret_cast<us8*>(msout + (size_t)bq * 256 + h * 32 + j * 8) = r;
}

// ---------------------------------------------------------------------------
extern "C" void kernel_launch(void* const* d_in, const int* in_sizes, int n_in,
                              void* d_out, int out_size, void* d_ws, size_t ws_size,
                              hipStream_t stream) {
    const float* query = (const float*)d_in[0];
    const float* qpos  = (const float*)d_in[1];
    const float* value = (const float*)d_in[2];
    const float* refp  = (const float*)d_in[3];
    const float* W_off  = (const float*)d_in[6];
    const float* b_off  = (const float*)d_in[7];
    const float* W_attn = (const float*)d_in[8];
    const float* b_attn = (const float*)d_in[9];
    const float* W_v    = (const float*)d_in[10];
    const float* b_v    = (const float*)d_in[11];
    const float* W_out  = (const float*)d_in[12];
    const float* b_out  = (const float*)d_in[13];
    const float* ln1_g  = (const float*)d_in[14];
    const float* ln1_b  = (const float*)d_in[15];
    const float* W1     = (const float*)d_in[16];
    const float* b1     = (const float*)d_in[17];
    const float* W2     = (const float*)d_in[18];
    const float* b2     = (const float*)d_in[19];
    const float* ln2_g  = (const float*)d_in[20];
    const float* ln2_b  = (const float*)d_in[21];
    float* out = (float*)d_out;

    // ---- workspace layout ----
    unsigned short* WvT   = (unsigned short*)d_ws;
    unsigned short* WoaT  = WvT   + 65536;    // 384 x 256  (off | attn)
    unsigned short* WoutT = WoaT  + 98304;
    unsigned short* W1T   = WoutT + 65536;    // 1024 x 256
    unsigned short* W2T   = W1T   + 262144;   // 256 x 1024
    float* b_oa = (float*)(W2T + 262144);     // 384 f32
    uint8_t* base = (uint8_t*)(b_oa + 384);
    base = (uint8_t*)(((uintptr_t)base + 255) & ~(uintptr_t)255);

    const size_t A = (size_t)M_ * D_;
    unsigned short* R_v16  = (unsigned short*)base;          // value bf16 -> q1b (LN1 out)
    unsigned short* R_q16  = R_v16 + A;                      // q bf16 -> ms16
    unsigned short* R_vph  = R_q16 + A;                      // vproj bf16 head-major
    float* R_oa  = (float*)(R_vph + A);                      // off|attn (M,384)

    const dim3 blk(256);
    auto cdiv = [](size_t a, size_t b) { return (unsigned)((a + b - 1) / b); };

    const int n4 = (int)(A / 4);
    prep_kernel<<<cdiv(754048 + 2 * (size_t)n4, 256), blk, 0, stream>>>(
        W_v, W_off, W_attn, W_out, W1, W2, b_off, b_attn, value, query, qpos,
        WvT, WoaT, WoutT, W1T, W2T, b_oa, R_v16, R_q16, n4);

    const unsigned MT = (M_ + 127) / 128;   // 168
    // vproj (head-major bf16, coalesced) + off|attn (f32), one swizzled dispatch
    gemm_pre<<<dim3(5, MT), blk, 0, stream>>>(
        R_v16, R_q16, WvT, WoaT, b_v, b_oa, R_vph, R_oa);
    // deformable attention -> ms16 (overwrites R_q16, dead)
    const unsigned nQC = cdiv(LQ_, 64);   // 168
    msdeform_kernel<<<dim3(nQC * 16), blk, 0, stream>>>(R_vph, R_oa, refp, R_q16);
    // q1b = bf16 LN(query + ms16@WoutT^T + b_out) -> R_v16 (value bf16 dead)
    gemm_ln1<<<dim3(cdiv(M_, 64)), dim3(512), 0, stream>>>(
        R_q16, WoutT, b_out, query, ln1_g, ln1_b, R_v16, M_, 256);
    // out = LN(q1b + relu(q1b@W1^T+b1)@W2^T + b2), fully fused (h stays on-chip)
    gemm_ffn_ln<<<dim3(cdiv(M_, 64)), dim3(512), 0, stream>>>(
        R_v16, W1T, b1, W2T, b2, ln2_g, ln2_b, out, M_);
}

// Round 13
// 137.404 us; speedup vs baseline: 1.0768x; 1.0768x over previous
//
#include <hip/hip_runtime.h>
#include <math.h>

#define B_   2
#define LQ_  10723
#define D_   256
#define NH_  8
#define HD_  32
#define NL_  4
#define NP_  4
#define DFF_ 1024
#define M_   (B_ * LQ_)   // 21446

typedef __attribute__((ext_vector_type(4))) float f32x4;
typedef __attribute__((ext_vector_type(8))) short short8;
typedef __attribute__((ext_vector_type(4))) unsigned short us4;
typedef __attribute__((ext_vector_type(8))) unsigned short us8;
typedef __attribute__((ext_vector_type(4))) unsigned int u32x4;

__device__ __forceinline__ unsigned short f2bf(float f) {
    union { float f; unsigned int u; } x; x.f = f;
    unsigned int r = x.u + 0x7FFF + ((x.u >> 16) & 1);   // RNE
    return (unsigned short)(r >> 16);
}
__device__ __forceinline__ float bf2f(unsigned short u) {
    union { unsigned int u; float f; } x; x.u = (unsigned int)u << 16;
    return x.f;
}
__device__ __forceinline__ float bflo(unsigned int u) {
    union { unsigned int u; float f; } x; x.u = u << 16; return x.f;
}
__device__ __forceinline__ float bfhi(unsigned int u) {
    union { unsigned int u; float f; } x; x.u = u & 0xffff0000u; return x.f;
}

#define AS3U(p) ((__attribute__((address_space(3))) unsigned int*)(uintptr_t)(p))
#define AS1U(p) ((const __attribute__((address_space(1))) unsigned int*)(uintptr_t)(p))

// ---------------------------------------------------------------------------
// Fused prep: weight transpose/convert + bias concat + activation convert.
// ---------------------------------------------------------------------------
__global__ __launch_bounds__(256) void prep_kernel(
    const float* __restrict__ Wv, const float* __restrict__ Woff,
    const float* __restrict__ Wattn, const float* __restrict__ Wout,
    const float* __restrict__ W1, const float* __restrict__ W2,
    const float* __restrict__ b_off, const float* __restrict__ b_attn,
    const float* __restrict__ value, const float* __restrict__ query,
    const float* __restrict__ qpos,
    unsigned short* __restrict__ WvT, unsigned short* __restrict__ WoaT,
    unsigned short* __restrict__ WoutT, unsigned short* __restrict__ W1T,
    unsigned short* __restrict__ W2T, float* __restrict__ b_oa,
    unsigned short* __restrict__ v16, unsigned short* __restrict__ q16, int n4)
{
    int idx = blockIdx.x * 256 + threadIdx.x;
    if (idx < 65536) {
        int n = idx >> 8, k = idx & 255;
        WvT[idx] = f2bf(Wv[k * 256 + n]);
    } else if (idx < 163840) {
        int l = idx - 65536; int n = l >> 8, k = l & 255;
        WoaT[l] = f2bf(n < 256 ? Woff[k * 256 + n] : Wattn[k * 128 + (n - 256)]);
    } else if (idx < 229376) {
        int l = idx - 163840; int n = l >> 8, k = l & 255;
        WoutT[l] = f2bf(Wout[k * 256 + n]);
    } else if (idx < 491520) {
        int l = idx - 229376; int n = l >> 8, k = l & 255;
        W1T[l] = f2bf(W1[k * 1024 + n]);
    } else if (idx < 753664) {
        int l = idx - 491520; int n = l >> 10, k = l & 1023;
        W2T[l] = f2bf(W2[k * 256 + n]);
    } else if (idx < 754048) {
        int l = idx - 753664;
        b_oa[l] = (l < 256) ? b_off[l] : b_attn[l - 256];
    } else if (idx < 754048 + n4) {
        int i = idx - 754048;
        float4 v = reinterpret_cast<const float4*>(value)[i];
        us4 r = { f2bf(v.x), f2bf(v.y), f2bf(v.z), f2bf(v.w) };
        reinterpret_cast<us4*>(v16)[i] = r;
    } else if (idx < 754048 + 2 * n4) {
        int j = idx - 754048 - n4;
        float4 va = reinterpret_cast<const float4*>(query)[j];
        float4 vb = reinterpret_cast<const float4*>(qpos)[j];
        us4 r = { f2bf(va.x + vb.x), f2bf(va.y + vb.y), f2bf(va.z + vb.z), f2bf(va.w + vb.w) };
        reinterpret_cast<us4*>(q16)[j] = r;
    }
}

// ---------------------------------------------------------------------------
// Fused vproj + off/attn GEMM dispatch. 128x128 tile, BK=32, K=256, 2-phase.
// XCD-chunked swizzle: 840 blocks = 8 XCDs x (21 row-bands x 5 cols).
// Both outputs bf16 via LDS-staged coalesced epilogue.
// ---------------------------------------------------------------------------
__global__ __launch_bounds__(256) void gemm_pre(
    const unsigned short* __restrict__ v16, const unsigned short* __restrict__ q16,
    const unsigned short* __restrict__ WvT, const unsigned short* __restrict__ WoaT,
    const float* __restrict__ b_v, const float* __restrict__ b_oa,
    unsigned short* __restrict__ vph, unsigned short* __restrict__ oa16)
{
    __shared__ unsigned short SM[2][2][128 * 32];

    const int i   = (int)blockIdx.y * 5 + (int)blockIdx.x;
    const int xcd = i & 7;
    const int jj  = i >> 3;            // 0..104
    const int by  = xcd * 21 + jj / 5;
    const int bx  = jj % 5;

    const bool is_v = (bx < 2);
    const unsigned short* A  = is_v ? v16 : q16;
    const unsigned short* BT = is_v ? WvT : WoaT;
    const float* bias = is_v ? b_v : b_oa;
    const int n0 = (is_v ? bx : bx - 2) * 128;
    const int K = 256;

    const int tid  = threadIdx.x;
    const int wave = tid >> 6;
    const int lane = tid & 63;
    const int m0 = by * 128;
    const int wr = (wave >> 1) * 64;
    const int wc = (wave & 1) * 64;

    f32x4 acc[4][4] = {};
    const int soff = wave * 1024 + lane * 16;

    auto stage = [&](int buf, int k0) {
        #pragma unroll
        for (int p = 0; p < 2; ++p) {
            const int off  = p * 4096 + soff;
            const int row  = off >> 6;
            const int colb = off & 63;
            int ar = m0 + row; ar = (ar < M_) ? ar : (M_ - 1);
            __builtin_amdgcn_global_load_lds(AS1U(A + (size_t)ar * K + k0 + (colb >> 1)),
                AS3U(&SM[0][buf][(p * 4096 + wave * 1024) >> 1]), 16, 0, 0);
            __builtin_amdgcn_global_load_lds(AS1U(BT + (size_t)(n0 + row) * K + k0 + (colb >> 1)),
                AS3U(&SM[1][buf][(p * 4096 + wave * 1024) >> 1]), 16, 0, 0);
        }
    };

    stage(0, 0);
    __syncthreads();
    int cur = 0;
    for (int t = 0; t < 8; ++t) {
        if (t + 1 < 8) stage(cur ^ 1, (t + 1) * 32);
        const int fr = lane & 15;
        const int kb = (lane >> 4) * 8;
        short8 af[4], bf[4];
        #pragma unroll
        for (int m = 0; m < 4; ++m)
            af[m] = *reinterpret_cast<const short8*>(&SM[0][cur][(wr + m * 16 + fr) * 32 + kb]);
        #pragma unroll
        for (int n = 0; n < 4; ++n)
            bf[n] = *reinterpret_cast<const short8*>(&SM[1][cur][(wc + n * 16 + fr) * 32 + kb]);
        #pragma unroll
        for (int m = 0; m < 4; ++m)
            #pragma unroll
            for (int n = 0; n < 4; ++n)
                acc[m][n] = __builtin_amdgcn_mfma_f32_16x16x32_bf16(af[m], bf[n], acc[m][n], 0, 0, 0);
        if (t + 1 < 8) { __syncthreads(); cur ^= 1; }
    }

    const int fr = lane & 15;
    const int r0 = (lane >> 4) * 4;
    // ---- LDS-staged coalesced bf16 epilogue (both paths) ----
    __syncthreads();
    unsigned short* Ct = &SM[0][0][0];   // 128x128 bf16 = 32 KB
    #pragma unroll
    for (int n = 0; n < 4; ++n) {
        const float bv = bias[n0 + wc + n * 16 + fr];
        #pragma unroll
        for (int m = 0; m < 4; ++m)
            #pragma unroll
            for (int r = 0; r < 4; ++r)
                Ct[(wr + m * 16 + r0 + r) * 128 + wc + n * 16 + fr] = f2bf(acc[m][n][r] + bv);
    }
    __syncthreads();
    #pragma unroll
    for (int pass = 0; pass < 8; ++pass) {
        const int r  = pass * 16 + (tid >> 4);
        const int c8 = (tid & 15) * 8;
        const int row = m0 + r;
        if (row < M_) {
            const int col = n0 + c8;
            us8 v = *reinterpret_cast<const us8*>(&Ct[r * 128 + c8]);
            if (is_v) {
                const int bb = (row >= LQ_) ? 1 : 0;
                const int lvv = row - bb * LQ_;
                const int hh = col >> 5, dd = col & 31;
                *reinterpret_cast<us8*>(&vph[(((size_t)bb * NH_ + hh) * LQ_ + lvv) * 32 + dd]) = v;
            } else {
                *reinterpret_cast<us8*>(&oa16[(size_t)row * 384 + col]) = v;
            }
        }
    }
}

// ---------------------------------------------------------------------------
// FFN1 GEMM: 128x128 tile, BK=32, 2-phase dbuf, XCD-chunked swizzle (NX=8),
// relu + bf16 output via LDS-staged coalesced epilogue.
// ---------------------------------------------------------------------------
__global__ __launch_bounds__(256) void gemm_ffn1(
    const unsigned short* __restrict__ A,
    const unsigned short* __restrict__ BT,
    const float* __restrict__ bias,
    unsigned short* __restrict__ Cout,
    int M, int N, int K)
{
    __shared__ unsigned short SM[2][2][128 * 32];

    const int i   = (int)blockIdx.y * 8 + (int)blockIdx.x;
    const int xcd = i & 7;
    const int jj  = i >> 3;            // 0..167
    const int by  = xcd * 21 + (jj >> 3);
    const int bx  = jj & 7;

    const int tid  = threadIdx.x;
    const int wave = tid >> 6;
    const int lane = tid & 63;
    const int m0 = by * 128;
    const int n0 = bx * 128;
    const int wr = (wave >> 1) * 64;
    const int wc = (wave & 1) * 64;

    f32x4 acc[4][4] = {};
    const int soff = wave * 1024 + lane * 16;

    auto stage = [&](int buf, int k0) {
        #pragma unroll
        for (int p = 0; p < 2; ++p) {
            const int off  = p * 4096 + soff;
            const int row  = off >> 6;
            const int colb = off & 63;
            int ar = m0 + row; ar = (ar < M) ? ar : (M - 1);
            __builtin_amdgcn_global_load_lds(AS1U(A + (size_t)ar * K + k0 + (colb >> 1)),
                AS3U(&SM[0][buf][(p * 4096 + wave * 1024) >> 1]), 16, 0, 0);
            __builtin_amdgcn_global_load_lds(AS1U(BT + (size_t)(n0 + row) * K + k0 + (colb >> 1)),
                AS3U(&SM[1][buf][(p * 4096 + wave * 1024) >> 1]), 16, 0, 0);
        }
    };

    const int nt = K >> 5;
    stage(0, 0);
    __syncthreads();
    int cur = 0;
    for (int t = 0; t < nt; ++t) {
        if (t + 1 < nt) stage(cur ^ 1, (t + 1) * 32);
        const int fr = lane & 15;
        const int kb = (lane >> 4) * 8;
        short8 af[4], bf[4];
        #pragma unroll
        for (int m = 0; m < 4; ++m)
            af[m] = *reinterpret_cast<const short8*>(&SM[0][cur][(wr + m * 16 + fr) * 32 + kb]);
        #pragma unroll
        for (int n = 0; n < 4; ++n)
            bf[n] = *reinterpret_cast<const short8*>(&SM[1][cur][(wc + n * 16 + fr) * 32 + kb]);
        #pragma unroll
        for (int m = 0; m < 4; ++m)
            #pragma unroll
            for (int n = 0; n < 4; ++n)
                acc[m][n] = __builtin_amdgcn_mfma_f32_16x16x32_bf16(af[m], bf[n], acc[m][n], 0, 0, 0);
        if (t + 1 < nt) { __syncthreads(); cur ^= 1; }
    }

    const int fr = lane & 15;
    const int r0 = (lane >> 4) * 4;
    __syncthreads();
    unsigned short* Ct = &SM[0][0][0];
    #pragma unroll
    for (int n = 0; n < 4; ++n) {
        const float bv = bias[n0 + wc + n * 16 + fr];
        #pragma unroll
        for (int m = 0; m < 4; ++m)
            #pragma unroll
            for (int r = 0; r < 4; ++r)
                Ct[(wr + m * 16 + r0 + r) * 128 + wc + n * 16 + fr] = f2bf(fmaxf(acc[m][n][r] + bv, 0.f));
    }
    __syncthreads();
    #pragma unroll
    for (int pass = 0; pass < 8; ++pass) {
        const int r  = pass * 16 + (tid >> 4);
        const int c8 = (tid & 15) * 8;
        const int row = m0 + r;
        if (row < M) {
            us8 v = *reinterpret_cast<const us8*>(&Ct[r * 128 + c8]);
            *reinterpret_cast<us8*>(&Cout[(size_t)row * N + n0 + c8]) = v;
        }
    }
}

// ---------------------------------------------------------------------------
// GEMM (N=256) + bias + residual + LayerNorm, fused. 2-phase double-buffered.
// BM=64, BN=256, BK=32, 512 threads = 8 waves.
// RES_BF16: residual dtype. OUT_F32: 1 = f32 direct; 0 = bf16 LDS-coalesced.
// ---------------------------------------------------------------------------
template<int RES_BF16, int OUT_F32>
__global__ __launch_bounds__(512) void gemm_ln(
    const unsigned short* __restrict__ A,
    const unsigned short* __restrict__ BT,
    const float* __restrict__ bias,
    const void* __restrict__ resp,
    const float* __restrict__ g,
    const float* __restrict__ beta,
    void* __restrict__ outp,
    int M, int K)
{
    __shared__ unsigned short As[2][64 * 32];
    __shared__ unsigned short Bs[2][256 * 32];   // doubles as 64x256 bf16 out tile
    __shared__ float2 sRed[4][64];

    const int tid  = threadIdx.x;
    const int wave = tid >> 6;
    const int lane = tid & 63;
    const int m0 = blockIdx.x * 64;
    const int wr = (wave >> 2) * 32;
    const int wc = (wave & 3) * 64;

    f32x4 acc[2][4] = {};

    auto stage = [&](int buf, int k0) {
        if (tid < 256) {
            const int off  = tid * 16;
            const int row  = off >> 6;
            const int colb = off & 63;
            int ar = m0 + row; ar = (ar < M) ? ar : (M - 1);
            __builtin_amdgcn_global_load_lds(AS1U(A + (size_t)ar * K + k0 + (colb >> 1)),
                AS3U(&As[buf][(wave * 1024) >> 1]), 16, 0, 0);
        }
        #pragma unroll
        for (int p = 0; p < 2; ++p) {
            const int off  = p * 8192 + tid * 16;
            const int row  = off >> 6;
            const int colb = off & 63;
            __builtin_amdgcn_global_load_lds(AS1U(BT + (size_t)row * K + k0 + (colb >> 1)),
                AS3U(&Bs[buf][(p * 8192 + wave * 1024) >> 1]), 16, 0, 0);
        }
    };

    const int nt = K >> 5;
    stage(0, 0);
    __syncthreads();
    int cur = 0;
    for (int t = 0; t < nt; ++t) {
        if (t + 1 < nt) stage(cur ^ 1, (t + 1) * 32);
        const int fr = lane & 15;
        const int kb = (lane >> 4) * 8;
        short8 af[2], bf[4];
        #pragma unroll
        for (int m = 0; m < 2; ++m)
            af[m] = *reinterpret_cast<const short8*>(&As[cur][(wr + m * 16 + fr) * 32 + kb]);
        #pragma unroll
        for (int n = 0; n < 4; ++n)
            bf[n] = *reinterpret_cast<const short8*>(&Bs[cur][(wc + n * 16 + fr) * 32 + kb]);
        #pragma unroll
        for (int m = 0; m < 2; ++m)
            #pragma unroll
            for (int n = 0; n < 4; ++n)
                acc[m][n] = __builtin_amdgcn_mfma_f32_16x16x32_bf16(af[m], bf[n], acc[m][n], 0, 0, 0);
        if (t + 1 < nt) { __syncthreads(); cur ^= 1; }
    }

    const int fr = lane & 15;
    const int r0 = (lane >> 4) * 4;
    float biasv[4], gv[4], bev[4];
    #pragma unroll
    for (int n = 0; n < 4; ++n) {
        const int col = wc + n * 16 + fr;
        biasv[n] = bias[col]; gv[n] = g[col]; bev[n] = beta[col];
    }
    #pragma unroll
    for (int m = 0; m < 2; ++m) {
        #pragma unroll
        for (int r = 0; r < 4; ++r) {
            int row = m0 + wr + m * 16 + r0 + r;
            int rr = (row < M) ? row : (M - 1);
            if (RES_BF16) {
                const unsigned short* rp = (const unsigned short*)resp + (size_t)rr * 256;
                #pragma unroll
                for (int n = 0; n < 4; ++n)
                    acc[m][n][r] += biasv[n] + bf2f(rp[wc + n * 16 + fr]);
            } else {
                const float* rp = (const float*)resp + (size_t)rr * 256;
                #pragma unroll
                for (int n = 0; n < 4; ++n)
                    acc[m][n][r] += biasv[n] + rp[wc + n * 16 + fr];
            }
        }
    }
    #pragma unroll
    for (int m = 0; m < 2; ++m) {
        #pragma unroll
        for (int r = 0; r < 4; ++r) {
            float sx = 0.f, sxx = 0.f;
            #pragma unroll
            for (int n = 0; n < 4; ++n) { float t = acc[m][n][r]; sx += t; sxx += t * t; }
            #pragma unroll
            for (int mask = 1; mask < 16; mask <<= 1) {
                sx  += __shfl_xor(sx, mask);
                sxx += __shfl_xor(sxx, mask);
            }
            if (fr == 0) sRed[wave & 3][wr + m * 16 + r0 + r] = make_float2(sx, sxx);
        }
    }
    __syncthreads();
    unsigned short* Ct = &Bs[0][0];   // 64x256 bf16
    #pragma unroll
    for (int m = 0; m < 2; ++m) {
        #pragma unroll
        for (int r = 0; r < 4; ++r) {
            const int lr = wr + m * 16 + r0 + r;
            float2 a0 = sRed[0][lr], a1 = sRed[1][lr], a2 = sRed[2][lr], a3 = sRed[3][lr];
            const float S  = a0.x + a1.x + a2.x + a3.x;
            const float SS = a0.y + a1.y + a2.y + a3.y;
            const float mean = S * (1.f / 256.f);
            const float var  = SS * (1.f / 256.f) - mean * mean;
            const float rstd = rsqrtf(var + 1e-5f);
            const int row = m0 + lr;
            #pragma unroll
            for (int n = 0; n < 4; ++n) {
                const int col = wc + n * 16 + fr;
                const float y = (acc[m][n][r] - mean) * rstd * gv[n] + bev[n];
                if (OUT_F32) {
                    if (row < M) ((float*)outp)[(size_t)row * 256 + col] = y;
                } else {
                    Ct[lr * 256 + col] = f2bf(y);
                }
            }
        }
    }
    if (!OUT_F32) {
        __syncthreads();
        unsigned short* o16 = (unsigned short*)outp;
        #pragma unroll
        for (int pass = 0; pass < 4; ++pass) {
            const int rrow = pass * 16 + (tid >> 5);
            const int cb = (tid & 31) * 8;
            const int grow = m0 + rrow;
            if (grow < M) {
                us8 v = *reinterpret_cast<const us8*>(&Ct[rrow * 256 + cb]);
                *reinterpret_cast<us8*>(&o16[(size_t)grow * 256 + cb]) = v;
            }
        }
    }
}

// ---------------------------------------------------------------------------
// Multi-scale deformable attention, XCD-local by head (round-9 structure:
// 4 lanes/query x 16B, depth-2 pipelined gathers). offattn now bf16 (M,384).
// ---------------------------------------------------------------------------
__global__ __launch_bounds__(256) void msdeform_kernel(
    const unsigned short* __restrict__ vproj_h, const unsigned short* __restrict__ offattn,
    const float* __restrict__ refp, unsigned short* __restrict__ msout)
{
    __shared__ int4   sIdx[4][16][17];
    __shared__ float4 sWgt[4][16][17];

    const int bh = blockIdx.x & 15;          // b*8 + h
    const int qc = blockIdx.x >> 4;
    const int b  = bh >> 3;
    const int h  = bh & 7;
    const int wave = threadIdx.x >> 6;
    const int lane = threadIdx.x & 63;
    const int qq = lane >> 2;                // query within wave (0..15)
    const int j  = lane & 3;                 // level (ph1) / channel-octet (ph2)
    const int lv = qc * 64 + wave * 16 + qq;
    if (lv >= LQ_) return;
    const int bq = b * LQ_ + lv;

    // ---- phase 1: level j, points 4j..4j+3 (bf16 offsets/logits) ----
    const unsigned short* oaRow = offattn + (size_t)bq * 384;
    const us8 o8 = *reinterpret_cast<const us8*>(oaRow + h * 32 + 8 * j);
    const us4 l4 = *reinterpret_cast<const us4*>(oaRow + 256 + h * 16 + 4 * j);
    const float2 rp = *reinterpret_cast<const float2*>(refp + (size_t)bq * 8 + 2 * j);

    const float Wf[4] = {106.f, 53.f, 27.f, 14.f};
    const float Hf[4] = {76.f, 38.f, 19.f, 10.f};
    const int   Wi[4] = {106, 53, 27, 14};
    const int   Hi[4] = {76, 38, 19, 10};
    const int   St[4] = {0, 8056, 10070, 10583};

    const float lgv[4] = {bf2f(l4.x), bf2f(l4.y), bf2f(l4.z), bf2f(l4.w)};
    float mx = fmaxf(fmaxf(lgv[0], lgv[1]), fmaxf(lgv[2], lgv[3]));
    mx = fmaxf(mx, __shfl_xor(mx, 1));
    mx = fmaxf(mx, __shfl_xor(mx, 2));
    const float e0 = __expf(lgv[0] - mx), e1 = __expf(lgv[1] - mx);
    const float e2 = __expf(lgv[2] - mx), e3 = __expf(lgv[3] - mx);
    float s = e0 + e1 + e2 + e3;
    s += __shfl_xor(s, 1); s += __shfl_xor(s, 2);
    const float inv = 1.f / s;

    const int W = Wi[j], H = Hi[j];
    const float Wff = Wf[j], Hff = Hf[j];
    const int base = St[j];
    const float oxs[4] = {bf2f(o8[0]), bf2f(o8[2]), bf2f(o8[4]), bf2f(o8[6])};
    const float oys[4] = {bf2f(o8[1]), bf2f(o8[3]), bf2f(o8[5]), bf2f(o8[7])};
    const float ews[4] = {e0, e1, e2, e3};

    #pragma unroll
    for (int i = 0; i < 4; ++i) {
        const float aw = ews[i] * inv;
        const float x = fmaf(rp.x, Wff, oxs[i]) - 0.5f;
        const float y = fmaf(rp.y, Hff, oys[i]) - 0.5f;
        const float xf = floorf(x), yf = floorf(y);
        const float fx = x - xf, fy = y - yf;
        const int x0 = (int)xf, y0 = (int)yf;
        const float gx = 1.f - fx, gy = 1.f - fy;
        const bool vx0 = (x0 >= 0) && (x0 < W);
        const bool vx1 = (x0 + 1 >= 0) && (x0 + 1 < W);
        const bool vy0 = (y0 >= 0) && (y0 < H);
        const bool vy1 = (y0 + 1 >= 0) && (y0 + 1 < H);
        const int xc0 = min(max(x0, 0), W - 1);
        const int xc1 = min(max(x0 + 1, 0), W - 1);
        const int yr0 = min(max(y0, 0), H - 1) * W;
        const int yr1 = min(max(y0 + 1, 0), H - 1) * W;
        int4 iv; float4 wv;
        iv.x = (base + yr0 + xc0) << 6;  wv.x = (vx0 && vy0) ? gx * gy * aw : 0.f;
        iv.y = (base + yr0 + xc1) << 6;  wv.y = (vx1 && vy0) ? fx * gy * aw : 0.f;
        iv.z = (base + yr1 + xc0) << 6;  wv.z = (vx0 && vy1) ? gx * fy * aw : 0.f;
        iv.w = (base + yr1 + xc1) << 6;  wv.w = (vx1 && vy1) ? fx * fy * aw : 0.f;
        sIdx[wave][qq][4 * j + i] = iv;
        sWgt[wave][qq][4 * j + i] = wv;
    }

    // ---- phase 2: depth-2 pipelined gather, 16 B/lane/corner ----
    const char* vb = (const char*)(vproj_h + (size_t)bh * LQ_ * 32) + j * 16;
    f32x4 accA = {0.f, 0.f, 0.f, 0.f};
    f32x4 accB = {0.f, 0.f, 0.f, 0.f};

    int4 iv0 = sIdx[wave][qq][0];
    u32x4 a0 = *reinterpret_cast<const u32x4*>(vb + (unsigned)iv0.x);
    u32x4 a1 = *reinterpret_cast<const u32x4*>(vb + (unsigned)iv0.y);
    u32x4 a2 = *reinterpret_cast<const u32x4*>(vb + (unsigned)iv0.z);
    u32x4 a3 = *reinterpret_cast<const u32x4*>(vb + (unsigned)iv0.w);

    #pragma unroll
    for (int p = 0; p < 16; ++p) {
        u32x4 b0, b1, b2, b3;
        if (p < 15) {
            const int4 nv = sIdx[wave][qq][p + 1];
            b0 = *reinterpret_cast<const u32x4*>(vb + (unsigned)nv.x);
            b1 = *reinterpret_cast<const u32x4*>(vb + (unsigned)nv.y);
            b2 = *reinterpret_cast<const u32x4*>(vb + (unsigned)nv.z);
            b3 = *reinterpret_cast<const u32x4*>(vb + (unsigned)nv.w);
        }
        const float4 wv = sWgt[wave][qq][p];
        accA[0] = fmaf(wv.x, bflo(a0.x), accA[0]); accA[1] = fmaf(wv.x, bfhi(a0.x), accA[1]);
        accA[2] = fmaf(wv.x, bflo(a0.y), accA[2]); accA[3] = fmaf(wv.x, bfhi(a0.y), accA[3]);
        accB[0] = fmaf(wv.x, bflo(a0.z), accB[0]); accB[1] = fmaf(wv.x, bfhi(a0.z), accB[1]);
        accB[2] = fmaf(wv.x, bflo(a0.w), accB[2]); accB[3] = fmaf(wv.x, bfhi(a0.w), accB[3]);
        accA[0] = fmaf(wv.y, bflo(a1.x), accA[0]); accA[1] = fmaf(wv.y, bfhi(a1.x), accA[1]);
        accA[2] = fmaf(wv.y, bflo(a1.y), accA[2]); accA[3] = fmaf(wv.y, bfhi(a1.y), accA[3]);
        accB[0] = fmaf(wv.y, bflo(a1.z), accB[0]); accB[1] = fmaf(wv.y, bfhi(a1.z), accB[1]);
        accB[2] = fmaf(wv.y, bflo(a1.w), accB[2]); accB[3] = fmaf(wv.y, bfhi(a1.w), accB[3]);
        accA[0] = fmaf(wv.z, bflo(a2.x), accA[0]); accA[1] = fmaf(wv.z, bfhi(a2.x), accA[1]);
        accA[2] = fmaf(wv.z, bflo(a2.y), accA[2]); accA[3] = fmaf(wv.z, bfhi(a2.y), accA[3]);
        accB[0] = fmaf(wv.z, bflo(a2.z), accB[0]); accB[1] = fmaf(wv.z, bfhi(a2.z), accB[1]);
        accB[2] = fmaf(wv.z, bflo(a2.w), accB[2]); accB[3] = fmaf(wv.z, bfhi(a2.w), accB[3]);
        accA[0] = fmaf(wv.w, bflo(a3.x), accA[0]); accA[1] = fmaf(wv.w, bfhi(a3.x), accA[1]);
        accA[2] = fmaf(wv.w, bflo(a3.y), accA[2]); accA[3] = fmaf(wv.w, bfhi(a3.y), accA[3]);
        accB[0] = fmaf(wv.w, bflo(a3.z), accB[0]); accB[1] = fmaf(wv.w, bfhi(a3.z), accB[1]);
        accB[2] = fmaf(wv.w, bflo(a3.w), accB[2]); accB[3] = fmaf(wv.w, bfhi(a3.w), accB[3]);
        a0 = b0; a1 = b1; a2 = b2; a3 = b3;
    }
    us8 r = { f2bf(accA[0]), f2bf(accA[1]), f2bf(accA[2]), f2bf(accA[3]),
              f2bf(accB[0]), f2bf(accB[1]), f2bf(accB[2]), f2bf(accB[3]) };
    *reinterpret_cast<us8*>(msout + (size_t)bq * 256 + h * 32 + j * 8) = r;
}

// ---------------------------------------------------------------------------
extern "C" void kernel_launch(void* const* d_in, const int* in_sizes, int n_in,
                              void* d_out, int out_size, void* d_ws, size_t ws_size,
                              hipStream_t stream) {
    const float* query = (const float*)d_in[0];
    const float* qpos  = (const float*)d_in[1];
    const float* value = (const float*)d_in[2];
    const float* refp  = (const float*)d_in[3];
    const float* W_off  = (const float*)d_in[6];
    const float* b_off  = (const float*)d_in[7];
    const float* W_attn = (const float*)d_in[8];
    const float* b_attn = (const float*)d_in[9];
    const float* W_v    = (const float*)d_in[10];
    const float* b_v    = (const float*)d_in[11];
    const float* W_out  = (const float*)d_in[12];
    const float* b_out  = (const float*)d_in[13];
    const float* ln1_g  = (const float*)d_in[14];
    const float* ln1_b  = (const float*)d_in[15];
    const float* W1     = (const float*)d_in[16];
    const float* b1     = (const float*)d_in[17];
    const float* W2     = (const float*)d_in[18];
    const float* b2     = (const float*)d_in[19];
    const float* ln2_g  = (const float*)d_in[20];
    const float* ln2_b  = (const float*)d_in[21];
    float* out = (float*)d_out;

    // ---- workspace layout ----
    unsigned short* WvT   = (unsigned short*)d_ws;
    unsigned short* WoaT  = WvT   + 65536;    // 384 x 256  (off | attn)
    unsigned short* WoutT = WoaT  + 98304;
    unsigned short* W1T   = WoutT + 65536;    // 1024 x 256
    unsigned short* W2T   = W1T   + 262144;   // 256 x 1024
    float* b_oa = (float*)(W2T + 262144);     // 384 f32
    uint8_t* base = (uint8_t*)(b_oa + 384);
    base = (uint8_t*)(((uintptr_t)base + 255) & ~(uintptr_t)255);

    const size_t A = (size_t)M_ * D_;
    unsigned short* R_v16  = (unsigned short*)base;          // value bf16 -> q1b (LN1 out)
    unsigned short* R_q16  = R_v16 + A;                      // q bf16 -> ms16
    unsigned short* R_vph  = R_q16 + A;                      // vproj bf16 head-major
    unsigned short* R_oa16 = R_vph + A;                      // off|attn (M,384) bf16
    unsigned short* R_h16  = R_oa16 + (size_t)M_ * 384;      // FFN hidden bf16 (M,1024)

    const dim3 blk(256);
    auto cdiv = [](size_t a, size_t b) { return (unsigned)((a + b - 1) / b); };

    const int n4 = (int)(A / 4);
    prep_kernel<<<cdiv(754048 + 2 * (size_t)n4, 256), blk, 0, stream>>>(
        W_v, W_off, W_attn, W_out, W1, W2, b_off, b_attn, value, query, qpos,
        WvT, WoaT, WoutT, W1T, W2T, b_oa, R_v16, R_q16, n4);

    const unsigned MT = (M_ + 127) / 128;   // 168
    // vproj (head-major bf16) + off|attn (bf16), one swizzled dispatch
    gemm_pre<<<dim3(5, MT), blk, 0, stream>>>(
        R_v16, R_q16, WvT, WoaT, b_v, b_oa, R_vph, R_oa16);
    // deformable attention -> ms16 (overwrites R_q16, dead)
    const unsigned nQC = cdiv(LQ_, 64);   // 168
    msdeform_kernel<<<dim3(nQC * 16), blk, 0, stream>>>(R_vph, R_oa16, refp, R_q16);
    // q1b = bf16 LN(query + ms16@WoutT^T + b_out) -> R_v16 (value bf16 dead)
    gemm_ln<0, 0><<<dim3(cdiv(M_, 64)), dim3(512), 0, stream>>>(
        R_q16, WoutT, b_out, query, ln1_g, ln1_b, R_v16, M_, 256);
    // h = relu(q1b @ W1T^T) bf16, swizzled + coalesced epilogue
    gemm_ffn1<<<dim3(8, MT), blk, 0, stream>>>(R_v16, W1T, b1, R_h16, M_, 1024, 256);
    // out = LN(q1b + h@W2T^T + b2), f32 direct
    gemm_ln<1, 1><<<dim3(cdiv(M_, 64)), dim3(512), 0, stream>>>(
        R_h16, W2T, b2, R_v16, ln2_g, ln2_b, out, M_, 1024);
}

// Round 14
// 136.355 us; speedup vs baseline: 1.0851x; 1.0077x over previous
//
#include <hip/hip_runtime.h>
#include <math.h>

#define B_   2
#define LQ_  10723
#define D_   256
#define NH_  8
#define HD_  32
#define NL_  4
#define NP_  4
#define DFF_ 1024
#define M_   (B_ * LQ_)   // 21446

typedef __attribute__((ext_vector_type(4))) float f32x4;
typedef __attribute__((ext_vector_type(2))) float f32x2;
typedef __attribute__((ext_vector_type(8))) short short8;
typedef __attribute__((ext_vector_type(4))) unsigned short us4;
typedef __attribute__((ext_vector_type(8))) unsigned short us8;
typedef __attribute__((ext_vector_type(4))) unsigned int u32x4;

__device__ __forceinline__ unsigned short f2bf(float f) {
    union { float f; unsigned int u; } x; x.f = f;
    unsigned int r = x.u + 0x7FFF + ((x.u >> 16) & 1);   // RNE
    return (unsigned short)(r >> 16);
}
__device__ __forceinline__ float bf2f(unsigned short u) {
    union { unsigned int u; float f; } x; x.u = (unsigned int)u << 16;
    return x.f;
}
__device__ __forceinline__ float bflo(unsigned int u) {
    union { unsigned int u; float f; } x; x.u = u << 16; return x.f;
}
__device__ __forceinline__ float bfhi(unsigned int u) {
    union { unsigned int u; float f; } x; x.u = u & 0xffff0000u; return x.f;
}

#define AS3U(p) ((__attribute__((address_space(3))) unsigned int*)(uintptr_t)(p))
#define AS1U(p) ((const __attribute__((address_space(1))) unsigned int*)(uintptr_t)(p))

// ---------------------------------------------------------------------------
// Fused prep: weight transpose/convert + bias concat + activation convert.
// ---------------------------------------------------------------------------
__global__ __launch_bounds__(256) void prep_kernel(
    const float* __restrict__ Wv, const float* __restrict__ Woff,
    const float* __restrict__ Wattn, const float* __restrict__ Wout,
    const float* __restrict__ W1, const float* __restrict__ W2,
    const float* __restrict__ b_off, const float* __restrict__ b_attn,
    const float* __restrict__ value, const float* __restrict__ query,
    const float* __restrict__ qpos,
    unsigned short* __restrict__ WvT, unsigned short* __restrict__ WoaT,
    unsigned short* __restrict__ WoutT, unsigned short* __restrict__ W1T,
    unsigned short* __restrict__ W2T, float* __restrict__ b_oa,
    unsigned short* __restrict__ v16, unsigned short* __restrict__ q16, int n4)
{
    int idx = blockIdx.x * 256 + threadIdx.x;
    if (idx < 65536) {
        int n = idx >> 8, k = idx & 255;
        WvT[idx] = f2bf(Wv[k * 256 + n]);
    } else if (idx < 163840) {
        int l = idx - 65536; int n = l >> 8, k = l & 255;
        WoaT[l] = f2bf(n < 256 ? Woff[k * 256 + n] : Wattn[k * 128 + (n - 256)]);
    } else if (idx < 229376) {
        int l = idx - 163840; int n = l >> 8, k = l & 255;
        WoutT[l] = f2bf(Wout[k * 256 + n]);
    } else if (idx < 491520) {
        int l = idx - 229376; int n = l >> 8, k = l & 255;
        W1T[l] = f2bf(W1[k * 1024 + n]);
    } else if (idx < 753664) {
        int l = idx - 491520; int n = l >> 10, k = l & 1023;
        W2T[l] = f2bf(W2[k * 256 + n]);
    } else if (idx < 754048) {
        int l = idx - 753664;
        b_oa[l] = (l < 256) ? b_off[l] : b_attn[l - 256];
    } else if (idx < 754048 + n4) {
        int i = idx - 754048;
        float4 v = reinterpret_cast<const float4*>(value)[i];
        us4 r = { f2bf(v.x), f2bf(v.y), f2bf(v.z), f2bf(v.w) };
        reinterpret_cast<us4*>(v16)[i] = r;
    } else if (idx < 754048 + 2 * n4) {
        int j = idx - 754048 - n4;
        float4 va = reinterpret_cast<const float4*>(query)[j];
        float4 vb = reinterpret_cast<const float4*>(qpos)[j];
        us4 r = { f2bf(va.x + vb.x), f2bf(va.y + vb.y), f2bf(va.z + vb.z), f2bf(va.w + vb.w) };
        reinterpret_cast<us4*>(q16)[j] = r;
    }
}

// ---------------------------------------------------------------------------
// Fused vproj + off/attn GEMM dispatch. 128x128 tile, BK=32, K=256, 2-phase.
// XCD-chunked swizzle: 840 blocks = 8 XCDs x (21 row-bands x 5 cols).
// Both outputs bf16 via LDS-staged coalesced epilogue.
// ---------------------------------------------------------------------------
__global__ __launch_bounds__(256) void gemm_pre(
    const unsigned short* __restrict__ v16, const unsigned short* __restrict__ q16,
    const unsigned short* __restrict__ WvT, const unsigned short* __restrict__ WoaT,
    const float* __restrict__ b_v, const float* __restrict__ b_oa,
    unsigned short* __restrict__ vph, unsigned short* __restrict__ oa16)
{
    __shared__ unsigned short SM[2][2][128 * 32];

    const int i   = (int)blockIdx.y * 5 + (int)blockIdx.x;
    const int xcd = i & 7;
    const int jj  = i >> 3;            // 0..104
    const int by  = xcd * 21 + jj / 5;
    const int bx  = jj % 5;

    const bool is_v = (bx < 2);
    const unsigned short* A  = is_v ? v16 : q16;
    const unsigned short* BT = is_v ? WvT : WoaT;
    const float* bias = is_v ? b_v : b_oa;
    const int n0 = (is_v ? bx : bx - 2) * 128;
    const int K = 256;

    const int tid  = threadIdx.x;
    const int wave = tid >> 6;
    const int lane = tid & 63;
    const int m0 = by * 128;
    const int wr = (wave >> 1) * 64;
    const int wc = (wave & 1) * 64;

    f32x4 acc[4][4] = {};
    const int soff = wave * 1024 + lane * 16;

    auto stage = [&](int buf, int k0) {
        #pragma unroll
        for (int p = 0; p < 2; ++p) {
            const int off  = p * 4096 + soff;
            const int row  = off >> 6;
            const int colb = off & 63;
            int ar = m0 + row; ar = (ar < M_) ? ar : (M_ - 1);
            __builtin_amdgcn_global_load_lds(AS1U(A + (size_t)ar * K + k0 + (colb >> 1)),
                AS3U(&SM[0][buf][(p * 4096 + wave * 1024) >> 1]), 16, 0, 0);
            __builtin_amdgcn_global_load_lds(AS1U(BT + (size_t)(n0 + row) * K + k0 + (colb >> 1)),
                AS3U(&SM[1][buf][(p * 4096 + wave * 1024) >> 1]), 16, 0, 0);
        }
    };

    stage(0, 0);
    __syncthreads();
    int cur = 0;
    for (int t = 0; t < 8; ++t) {
        if (t + 1 < 8) stage(cur ^ 1, (t + 1) * 32);
        const int fr = lane & 15;
        const int kb = (lane >> 4) * 8;
        short8 af[4], bf[4];
        #pragma unroll
        for (int m = 0; m < 4; ++m)
            af[m] = *reinterpret_cast<const short8*>(&SM[0][cur][(wr + m * 16 + fr) * 32 + kb]);
        #pragma unroll
        for (int n = 0; n < 4; ++n)
            bf[n] = *reinterpret_cast<const short8*>(&SM[1][cur][(wc + n * 16 + fr) * 32 + kb]);
        #pragma unroll
        for (int m = 0; m < 4; ++m)
            #pragma unroll
            for (int n = 0; n < 4; ++n)
                acc[m][n] = __builtin_amdgcn_mfma_f32_16x16x32_bf16(af[m], bf[n], acc[m][n], 0, 0, 0);
        if (t + 1 < 8) { __syncthreads(); cur ^= 1; }
    }

    const int fr = lane & 15;
    const int r0 = (lane >> 4) * 4;
    // ---- LDS-staged coalesced bf16 epilogue (both paths) ----
    __syncthreads();
    unsigned short* Ct = &SM[0][0][0];   // 128x128 bf16 = 32 KB
    #pragma unroll
    for (int n = 0; n < 4; ++n) {
        const float bv = bias[n0 + wc + n * 16 + fr];
        #pragma unroll
        for (int m = 0; m < 4; ++m)
            #pragma unroll
            for (int r = 0; r < 4; ++r)
                Ct[(wr + m * 16 + r0 + r) * 128 + wc + n * 16 + fr] = f2bf(acc[m][n][r] + bv);
    }
    __syncthreads();
    #pragma unroll
    for (int pass = 0; pass < 8; ++pass) {
        const int r  = pass * 16 + (tid >> 4);
        const int c8 = (tid & 15) * 8;
        const int row = m0 + r;
        if (row < M_) {
            const int col = n0 + c8;
            us8 v = *reinterpret_cast<const us8*>(&Ct[r * 128 + c8]);
            if (is_v) {
                const int bb = (row >= LQ_) ? 1 : 0;
                const int lvv = row - bb * LQ_;
                const int hh = col >> 5, dd = col & 31;
                *reinterpret_cast<us8*>(&vph[(((size_t)bb * NH_ + hh) * LQ_ + lvv) * 32 + dd]) = v;
            } else {
                *reinterpret_cast<us8*>(&oa16[(size_t)row * 384 + col]) = v;
            }
        }
    }
}

// ---------------------------------------------------------------------------
// FFN1 GEMM: 128x128 tile, BK=32, 2-phase dbuf, XCD-chunked swizzle (NX=8),
// relu + bf16 output via LDS-staged coalesced epilogue.
// ---------------------------------------------------------------------------
__global__ __launch_bounds__(256) void gemm_ffn1(
    const unsigned short* __restrict__ A,
    const unsigned short* __restrict__ BT,
    const float* __restrict__ bias,
    unsigned short* __restrict__ Cout,
    int M, int N, int K)
{
    __shared__ unsigned short SM[2][2][128 * 32];

    const int i   = (int)blockIdx.y * 8 + (int)blockIdx.x;
    const int xcd = i & 7;
    const int jj  = i >> 3;            // 0..167
    const int by  = xcd * 21 + (jj >> 3);
    const int bx  = jj & 7;

    const int tid  = threadIdx.x;
    const int wave = tid >> 6;
    const int lane = tid & 63;
    const int m0 = by * 128;
    const int n0 = bx * 128;
    const int wr = (wave >> 1) * 64;
    const int wc = (wave & 1) * 64;

    f32x4 acc[4][4] = {};
    const int soff = wave * 1024 + lane * 16;

    auto stage = [&](int buf, int k0) {
        #pragma unroll
        for (int p = 0; p < 2; ++p) {
            const int off  = p * 4096 + soff;
            const int row  = off >> 6;
            const int colb = off & 63;
            int ar = m0 + row; ar = (ar < M) ? ar : (M - 1);
            __builtin_amdgcn_global_load_lds(AS1U(A + (size_t)ar * K + k0 + (colb >> 1)),
                AS3U(&SM[0][buf][(p * 4096 + wave * 1024) >> 1]), 16, 0, 0);
            __builtin_amdgcn_global_load_lds(AS1U(BT + (size_t)(n0 + row) * K + k0 + (colb >> 1)),
                AS3U(&SM[1][buf][(p * 4096 + wave * 1024) >> 1]), 16, 0, 0);
        }
    };

    const int nt = K >> 5;
    stage(0, 0);
    __syncthreads();
    int cur = 0;
    for (int t = 0; t < nt; ++t) {
        if (t + 1 < nt) stage(cur ^ 1, (t + 1) * 32);
        const int fr = lane & 15;
        const int kb = (lane >> 4) * 8;
        short8 af[4], bf[4];
        #pragma unroll
        for (int m = 0; m < 4; ++m)
            af[m] = *reinterpret_cast<const short8*>(&SM[0][cur][(wr + m * 16 + fr) * 32 + kb]);
        #pragma unroll
        for (int n = 0; n < 4; ++n)
            bf[n] = *reinterpret_cast<const short8*>(&SM[1][cur][(wc + n * 16 + fr) * 32 + kb]);
        #pragma unroll
        for (int m = 0; m < 4; ++m)
            #pragma unroll
            for (int n = 0; n < 4; ++n)
                acc[m][n] = __builtin_amdgcn_mfma_f32_16x16x32_bf16(af[m], bf[n], acc[m][n], 0, 0, 0);
        if (t + 1 < nt) { __syncthreads(); cur ^= 1; }
    }

    const int fr = lane & 15;
    const int r0 = (lane >> 4) * 4;
    __syncthreads();
    unsigned short* Ct = &SM[0][0][0];
    #pragma unroll
    for (int n = 0; n < 4; ++n) {
        const float bv = bias[n0 + wc + n * 16 + fr];
        #pragma unroll
        for (int m = 0; m < 4; ++m)
            #pragma unroll
            for (int r = 0; r < 4; ++r)
                Ct[(wr + m * 16 + r0 + r) * 128 + wc + n * 16 + fr] = f2bf(fmaxf(acc[m][n][r] + bv, 0.f));
    }
    __syncthreads();
    #pragma unroll
    for (int pass = 0; pass < 8; ++pass) {
        const int r  = pass * 16 + (tid >> 4);
        const int c8 = (tid & 15) * 8;
        const int row = m0 + r;
        if (row < M) {
            us8 v = *reinterpret_cast<const us8*>(&Ct[r * 128 + c8]);
            *reinterpret_cast<us8*>(&Cout[(size_t)row * N + n0 + c8]) = v;
        }
    }
}

// ---------------------------------------------------------------------------
// GEMM (N=256) + bias + residual + LayerNorm, fused. 2-phase double-buffered.
// BM=64, BN=256, BK=32, 512 threads = 8 waves.
// RES_BF16: residual dtype. OUT_F32: 1 = f32 direct; 0 = bf16 LDS-coalesced.
// ---------------------------------------------------------------------------
template<int RES_BF16, int OUT_F32>
__global__ __launch_bounds__(512) void gemm_ln(
    const unsigned short* __restrict__ A,
    const unsigned short* __restrict__ BT,
    const float* __restrict__ bias,
    const void* __restrict__ resp,
    const float* __restrict__ g,
    const float* __restrict__ beta,
    void* __restrict__ outp,
    int M, int K)
{
    __shared__ unsigned short As[2][64 * 32];
    __shared__ unsigned short Bs[2][256 * 32];   // doubles as 64x256 bf16 out tile
    __shared__ float2 sRed[4][64];

    const int tid  = threadIdx.x;
    const int wave = tid >> 6;
    const int lane = tid & 63;
    const int m0 = blockIdx.x * 64;
    const int wr = (wave >> 2) * 32;
    const int wc = (wave & 3) * 64;

    f32x4 acc[2][4] = {};

    auto stage = [&](int buf, int k0) {
        if (tid < 256) {
            const int off  = tid * 16;
            const int row  = off >> 6;
            const int colb = off & 63;
            int ar = m0 + row; ar = (ar < M) ? ar : (M - 1);
            __builtin_amdgcn_global_load_lds(AS1U(A + (size_t)ar * K + k0 + (colb >> 1)),
                AS3U(&As[buf][(wave * 1024) >> 1]), 16, 0, 0);
        }
        #pragma unroll
        for (int p = 0; p < 2; ++p) {
            const int off  = p * 8192 + tid * 16;
            const int row  = off >> 6;
            const int colb = off & 63;
            __builtin_amdgcn_global_load_lds(AS1U(BT + (size_t)row * K + k0 + (colb >> 1)),
                AS3U(&Bs[buf][(p * 8192 + wave * 1024) >> 1]), 16, 0, 0);
        }
    };

    const int nt = K >> 5;
    stage(0, 0);
    __syncthreads();
    int cur = 0;
    for (int t = 0; t < nt; ++t) {
        if (t + 1 < nt) stage(cur ^ 1, (t + 1) * 32);
        const int fr = lane & 15;
        const int kb = (lane >> 4) * 8;
        short8 af[2], bf[4];
        #pragma unroll
        for (int m = 0; m < 2; ++m)
            af[m] = *reinterpret_cast<const short8*>(&As[cur][(wr + m * 16 + fr) * 32 + kb]);
        #pragma unroll
        for (int n = 0; n < 4; ++n)
            bf[n] = *reinterpret_cast<const short8*>(&Bs[cur][(wc + n * 16 + fr) * 32 + kb]);
        #pragma unroll
        for (int m = 0; m < 2; ++m)
            #pragma unroll
            for (int n = 0; n < 4; ++n)
                acc[m][n] = __builtin_amdgcn_mfma_f32_16x16x32_bf16(af[m], bf[n], acc[m][n], 0, 0, 0);
        if (t + 1 < nt) { __syncthreads(); cur ^= 1; }
    }

    const int fr = lane & 15;
    const int r0 = (lane >> 4) * 4;
    float biasv[4], gv[4], bev[4];
    #pragma unroll
    for (int n = 0; n < 4; ++n) {
        const int col = wc + n * 16 + fr;
        biasv[n] = bias[col]; gv[n] = g[col]; bev[n] = beta[col];
    }
    #pragma unroll
    for (int m = 0; m < 2; ++m) {
        #pragma unroll
        for (int r = 0; r < 4; ++r) {
            int row = m0 + wr + m * 16 + r0 + r;
            int rr = (row < M) ? row : (M - 1);
            if (RES_BF16) {
                const unsigned short* rp = (const unsigned short*)resp + (size_t)rr * 256;
                #pragma unroll
                for (int n = 0; n < 4; ++n)
                    acc[m][n][r] += biasv[n] + bf2f(rp[wc + n * 16 + fr]);
            } else {
                const float* rp = (const float*)resp + (size_t)rr * 256;
                #pragma unroll
                for (int n = 0; n < 4; ++n)
                    acc[m][n][r] += biasv[n] + rp[wc + n * 16 + fr];
            }
        }
    }
    #pragma unroll
    for (int m = 0; m < 2; ++m) {
        #pragma unroll
        for (int r = 0; r < 4; ++r) {
            float sx = 0.f, sxx = 0.f;
            #pragma unroll
            for (int n = 0; n < 4; ++n) { float t = acc[m][n][r]; sx += t; sxx += t * t; }
            #pragma unroll
            for (int mask = 1; mask < 16; mask <<= 1) {
                sx  += __shfl_xor(sx, mask);
                sxx += __shfl_xor(sxx, mask);
            }
            if (fr == 0) sRed[wave & 3][wr + m * 16 + r0 + r] = make_float2(sx, sxx);
        }
    }
    __syncthreads();
    unsigned short* Ct = &Bs[0][0];   // 64x256 bf16
    #pragma unroll
    for (int m = 0; m < 2; ++m) {
        #pragma unroll
        for (int r = 0; r < 4; ++r) {
            const int lr = wr + m * 16 + r0 + r;
            float2 a0 = sRed[0][lr], a1 = sRed[1][lr], a2 = sRed[2][lr], a3 = sRed[3][lr];
            const float S  = a0.x + a1.x + a2.x + a3.x;
            const float SS = a0.y + a1.y + a2.y + a3.y;
            const float mean = S * (1.f / 256.f);
            const float var  = SS * (1.f / 256.f) - mean * mean;
            const float rstd = rsqrtf(var + 1e-5f);
            const int row = m0 + lr;
            #pragma unroll
            for (int n = 0; n < 4; ++n) {
                const int col = wc + n * 16 + fr;
                const float y = (acc[m][n][r] - mean) * rstd * gv[n] + bev[n];
                if (OUT_F32) {
                    if (row < M) ((float*)outp)[(size_t)row * 256 + col] = y;
                } else {
                    Ct[lr * 256 + col] = f2bf(y);
                }
            }
        }
    }
    if (!OUT_F32) {
        __syncthreads();
        unsigned short* o16 = (unsigned short*)outp;
        #pragma unroll
        for (int pass = 0; pass < 4; ++pass) {
            const int rrow = pass * 16 + (tid >> 5);
            const int cb = (tid & 31) * 8;
            const int grow = m0 + rrow;
            if (grow < M) {
                us8 v = *reinterpret_cast<const us8*>(&Ct[rrow * 256 + cb]);
                *reinterpret_cast<us8*>(&o16[(size_t)grow * 256 + cb]) = v;
            }
        }
    }
}

// ---------------------------------------------------------------------------
// Multi-scale deformable attention, XCD-local by head.
// 4 lanes/query x 16B gathers; distance-2 prefetch (issue p+2 before
// consuming p) + packed-f32 (v_pk_fma) accumulation. offattn bf16 (M,384).
// ---------------------------------------------------------------------------
__global__ __launch_bounds__(256) void msdeform_kernel(
    const unsigned short* __restrict__ vproj_h, const unsigned short* __restrict__ offattn,
    const float* __restrict__ refp, unsigned short* __restrict__ msout)
{
    __shared__ int4   sIdx[4][16][17];
    __shared__ float4 sWgt[4][16][17];

    const int bh = blockIdx.x & 15;          // b*8 + h
    const int qc = blockIdx.x >> 4;
    const int b  = bh >> 3;
    const int h  = bh & 7;
    const int wave = threadIdx.x >> 6;
    const int lane = threadIdx.x & 63;
    const int qq = lane >> 2;                // query within wave (0..15)
    const int j  = lane & 3;                 // level (ph1) / channel-octet (ph2)
    const int lv = qc * 64 + wave * 16 + qq;
    if (lv >= LQ_) return;
    const int bq = b * LQ_ + lv;

    // ---- phase 1: level j, points 4j..4j+3 (bf16 offsets/logits) ----
    const unsigned short* oaRow = offattn + (size_t)bq * 384;
    const us8 o8 = *reinterpret_cast<const us8*>(oaRow + h * 32 + 8 * j);
    const us4 l4 = *reinterpret_cast<const us4*>(oaRow + 256 + h * 16 + 4 * j);
    const float2 rp = *reinterpret_cast<const float2*>(refp + (size_t)bq * 8 + 2 * j);

    const float Wf[4] = {106.f, 53.f, 27.f, 14.f};
    const float Hf[4] = {76.f, 38.f, 19.f, 10.f};
    const int   Wi[4] = {106, 53, 27, 14};
    const int   Hi[4] = {76, 38, 19, 10};
    const int   St[4] = {0, 8056, 10070, 10583};

    const float lgv[4] = {bf2f(l4.x), bf2f(l4.y), bf2f(l4.z), bf2f(l4.w)};
    float mx = fmaxf(fmaxf(lgv[0], lgv[1]), fmaxf(lgv[2], lgv[3]));
    mx = fmaxf(mx, __shfl_xor(mx, 1));
    mx = fmaxf(mx, __shfl_xor(mx, 2));
    const float e0 = __expf(lgv[0] - mx), e1 = __expf(lgv[1] - mx);
    const float e2 = __expf(lgv[2] - mx), e3 = __expf(lgv[3] - mx);
    float s = e0 + e1 + e2 + e3;
    s += __shfl_xor(s, 1); s += __shfl_xor(s, 2);
    const float inv = 1.f / s;

    const int W = Wi[j], H = Hi[j];
    const float Wff = Wf[j], Hff = Hf[j];
    const int base = St[j];
    const float oxs[4] = {bf2f(o8[0]), bf2f(o8[2]), bf2f(o8[4]), bf2f(o8[6])};
    const float oys[4] = {bf2f(o8[1]), bf2f(o8[3]), bf2f(o8[5]), bf2f(o8[7])};
    const float ews[4] = {e0, e1, e2, e3};

    #pragma unroll
    for (int i = 0; i < 4; ++i) {
        const float aw = ews[i] * inv;
        const float x = fmaf(rp.x, Wff, oxs[i]) - 0.5f;
        const float y = fmaf(rp.y, Hff, oys[i]) - 0.5f;
        const float xf = floorf(x), yf = floorf(y);
        const float fx = x - xf, fy = y - yf;
        const int x0 = (int)xf, y0 = (int)yf;
        const float gx = 1.f - fx, gy = 1.f - fy;
        const bool vx0 = (x0 >= 0) && (x0 < W);
        const bool vx1 = (x0 + 1 >= 0) && (x0 + 1 < W);
        const bool vy0 = (y0 >= 0) && (y0 < H);
        const bool vy1 = (y0 + 1 >= 0) && (y0 + 1 < H);
        const int xc0 = min(max(x0, 0), W - 1);
        const int xc1 = min(max(x0 + 1, 0), W - 1);
        const int yr0 = min(max(y0, 0), H - 1) * W;
        const int yr1 = min(max(y0 + 1, 0), H - 1) * W;
        int4 iv; float4 wv;
        iv.x = (base + yr0 + xc0) << 6;  wv.x = (vx0 && vy0) ? gx * gy * aw : 0.f;
        iv.y = (base + yr0 + xc1) << 6;  wv.y = (vx1 && vy0) ? fx * gy * aw : 0.f;
        iv.z = (base + yr1 + xc0) << 6;  wv.z = (vx0 && vy1) ? gx * fy * aw : 0.f;
        iv.w = (base + yr1 + xc1) << 6;  wv.w = (vx1 && vy1) ? fx * fy * aw : 0.f;
        sIdx[wave][qq][4 * j + i] = iv;
        sWgt[wave][qq][4 * j + i] = wv;
    }

    // ---- phase 2: distance-2 pipelined gather, packed-f32 accumulation ----
    const char* vb = (const char*)(vproj_h + (size_t)bh * LQ_ * 32) + j * 16;
    f32x2 acc0 = {0.f, 0.f}, acc1 = {0.f, 0.f}, acc2 = {0.f, 0.f}, acc3 = {0.f, 0.f};

    u32x4 buf[2][4];   // fully-unrolled loop -> static indexing (rule #20 safe)
    {
        const int4 iv = sIdx[wave][qq][0];
        buf[0][0] = *reinterpret_cast<const u32x4*>(vb + (unsigned)iv.x);
        buf[0][1] = *reinterpret_cast<const u32x4*>(vb + (unsigned)iv.y);
        buf[0][2] = *reinterpret_cast<const u32x4*>(vb + (unsigned)iv.z);
        buf[0][3] = *reinterpret_cast<const u32x4*>(vb + (unsigned)iv.w);
    }
    {
        const int4 iv = sIdx[wave][qq][1];
        buf[1][0] = *reinterpret_cast<const u32x4*>(vb + (unsigned)iv.x);
        buf[1][1] = *reinterpret_cast<const u32x4*>(vb + (unsigned)iv.y);
        buf[1][2] = *reinterpret_cast<const u32x4*>(vb + (unsigned)iv.z);
        buf[1][3] = *reinterpret_cast<const u32x4*>(vb + (unsigned)iv.w);
    }

    #pragma unroll
    for (int p = 0; p < 16; ++p) {
        const int cb = p & 1;
        // snapshot current point's data, then reissue this buffer for p+2
        u32x4 c0 = buf[cb][0], c1 = buf[cb][1], c2 = buf[cb][2], c3 = buf[cb][3];
        if (p + 2 < 16) {
            const int4 nv = sIdx[wave][qq][p + 2];
            buf[cb][0] = *reinterpret_cast<const u32x4*>(vb + (unsigned)nv.x);
            buf[cb][1] = *reinterpret_cast<const u32x4*>(vb + (unsigned)nv.y);
            buf[cb][2] = *reinterpret_cast<const u32x4*>(vb + (unsigned)nv.z);
            buf[cb][3] = *reinterpret_cast<const u32x4*>(vb + (unsigned)nv.w);
        }
        const float4 wv = sWgt[wave][qq][p];
        f32x2 w2;
        w2[0] = wv.x; w2[1] = wv.x;
        acc0 += w2 * f32x2{bflo(c0.x), bfhi(c0.x)};
        acc1 += w2 * f32x2{bflo(c0.y), bfhi(c0.y)};
        acc2 += w2 * f32x2{bflo(c0.z), bfhi(c0.z)};
        acc3 += w2 * f32x2{bflo(c0.w), bfhi(c0.w)};
        w2[0] = wv.y; w2[1] = wv.y;
        acc0 += w2 * f32x2{bflo(c1.x), bfhi(c1.x)};
        acc1 += w2 * f32x2{bflo(c1.y), bfhi(c1.y)};
        acc2 += w2 * f32x2{bflo(c1.z), bfhi(c1.z)};
        acc3 += w2 * f32x2{bflo(c1.w), bfhi(c1.w)};
        w2[0] = wv.z; w2[1] = wv.z;
        acc0 += w2 * f32x2{bflo(c2.x), bfhi(c2.x)};
        acc1 += w2 * f32x2{bflo(c2.y), bfhi(c2.y)};
        acc2 += w2 * f32x2{bflo(c2.z), bfhi(c2.z)};
        acc3 += w2 * f32x2{bflo(c2.w), bfhi(c2.w)};
        w2[0] = wv.w; w2[1] = wv.w;
        acc0 += w2 * f32x2{bflo(c3.x), bfhi(c3.x)};
        acc1 += w2 * f32x2{bflo(c3.y), bfhi(c3.y)};
        acc2 += w2 * f32x2{bflo(c3.z), bfhi(c3.z)};
        acc3 += w2 * f32x2{bflo(c3.w), bfhi(c3.w)};
    }
    us8 r = { f2bf(acc0[0]), f2bf(acc0[1]), f2bf(acc1[0]), f2bf(acc1[1]),
              f2bf(acc2[0]), f2bf(acc2[1]), f2bf(acc3[0]), f2bf(acc3[1]) };
    *reinterpret_cast<us8*>(msout + (size_t)bq * 256 + h * 32 + j * 8) = r;
}

// ---------------------------------------------------------------------------
extern "C" void kernel_launch(void* const* d_in, const int* in_sizes, int n_in,
                              void* d_out, int out_size, void* d_ws, size_t ws_size,
                              hipStream_t stream) {
    const float* query = (const float*)d_in[0];
    const float* qpos  = (const float*)d_in[1];
    const float* value = (const float*)d_in[2];
    const float* refp  = (const float*)d_in[3];
    const float* W_off  = (const float*)d_in[6];
    const float* b_off  = (const float*)d_in[7];
    const float* W_attn = (const float*)d_in[8];
    const float* b_attn = (const float*)d_in[9];
    const float* W_v    = (const float*)d_in[10];
    const float* b_v    = (const float*)d_in[11];
    const float* W_out  = (const float*)d_in[12];
    const float* b_out  = (const float*)d_in[13];
    const float* ln1_g  = (const float*)d_in[14];
    const float* ln1_b  = (const float*)d_in[15];
    const float* W1     = (const float*)d_in[16];
    const float* b1     = (const float*)d_in[17];
    const float* W2     = (const float*)d_in[18];
    const float* b2     = (const float*)d_in[19];
    const float* ln2_g  = (const float*)d_in[20];
    const float* ln2_b  = (const float*)d_in[21];
    float* out = (float*)d_out;

    // ---- workspace layout ----
    unsigned short* WvT   = (unsigned short*)d_ws;
    unsigned short* WoaT  = WvT   + 65536;    // 384 x 256  (off | attn)
    unsigned short* WoutT = WoaT  + 98304;
    unsigned short* W1T   = WoutT + 65536;    // 1024 x 256
    unsigned short* W2T   = W1T   + 262144;   // 256 x 1024
    float* b_oa = (float*)(W2T + 262144);     // 384 f32
    uint8_t* base = (uint8_t*)(b_oa + 384);
    base = (uint8_t*)(((uintptr_t)base + 255) & ~(uintptr_t)255);

    const size_t A = (size_t)M_ * D_;
    unsigned short* R_v16  = (unsigned short*)base;          // value bf16 -> q1b (LN1 out)
    unsigned short* R_q16  = R_v16 + A;                      // q bf16 -> ms16
    unsigned short* R_vph  = R_q16 + A;                      // vproj bf16 head-major
    unsigned short* R_oa16 = R_vph + A;                      // off|attn (M,384) bf16
    unsigned short* R_h16  = R_oa16 + (size_t)M_ * 384;      // FFN hidden bf16 (M,1024)

    const dim3 blk(256);
    auto cdiv = [](size_t a, size_t b) { return (unsigned)((a + b - 1) / b); };

    const int n4 = (int)(A / 4);
    prep_kernel<<<cdiv(754048 + 2 * (size_t)n4, 256), blk, 0, stream>>>(
        W_v, W_off, W_attn, W_out, W1, W2, b_off, b_attn, value, query, qpos,
        WvT, WoaT, WoutT, W1T, W2T, b_oa, R_v16, R_q16, n4);

    const unsigned MT = (M_ + 127) / 128;   // 168
    // vproj (head-major bf16) + off|attn (bf16), one swizzled dispatch
    gemm_pre<<<dim3(5, MT), blk, 0, stream>>>(
        R_v16, R_q16, WvT, WoaT, b_v, b_oa, R_vph, R_oa16);
    // deformable attention -> ms16 (overwrites R_q16, dead)
    const unsigned nQC = cdiv(LQ_, 64);   // 168
    msdeform_kernel<<<dim3(nQC * 16), blk, 0, stream>>>(R_vph, R_oa16, refp, R_q16);
    // q1b = bf16 LN(query + ms16@WoutT^T + b_out) -> R_v16 (value bf16 dead)
    gemm_ln<0, 0><<<dim3(cdiv(M_, 64)), dim3(512), 0, stream>>>(
        R_q16, WoutT, b_out, query, ln1_g, ln1_b, R_v16, M_, 256);
    // h = relu(q1b @ W1T^T) bf16, swizzled + coalesced epilogue
    gemm_ffn1<<<dim3(8, MT), blk, 0, stream>>>(R_v16, W1T, b1, R_h16, M_, 1024, 256);
    // out = LN(q1b + h@W2T^T + b2), f32 direct
    gemm_ln<1, 1><<<dim3(cdiv(M_, 64)), dim3(512), 0, stream>>>(
        R_h16, W2T, b2, R_v16, ln2_g, ln2_b, out, M_, 1024);
}